// Round 1
// baseline (1539.441 us; speedup 1.0000x reference)
//
#include <hip/hip_runtime.h>
#include <math.h>

#define NBAT 8
#define NC   256
#define NH   96
#define NW   96
#define NP   9216
#define NCQ  32
#define NKC  6
#define NL   192
#define NTOT 73728   // NBAT*NP

// ---------- bf16 helpers (storage only; all math fp32) ----------
__device__ __forceinline__ float bf2f(unsigned short h){
  return __uint_as_float(((unsigned)h) << 16);
}
__device__ __forceinline__ float bflo(unsigned u){ return __uint_as_float(u << 16); }
__device__ __forceinline__ float bfhi(unsigned u){ return __uint_as_float(u & 0xFFFF0000u); }
__device__ __forceinline__ unsigned short f2bf(float f){
  unsigned u = __float_as_uint(f);
  u += 0x7FFFu + ((u >> 16) & 1u);
  return (unsigned short)(u >> 16);
}

union F4 { float4 v; float a[4]; };

// ---------- reductions ----------
__device__ __forceinline__ float warpReduceSum(float v){
  #pragma unroll
  for (int m = 32; m; m >>= 1) v += __shfl_xor(v, m);
  return v;
}
__device__ __forceinline__ float warpReduceMax(float v){
  #pragma unroll
  for (int m = 32; m; m >>= 1) v = fmaxf(v, __shfl_xor(v, m));
  return v;
}
__device__ float blockReduceSum(float v){
  __shared__ float lds[8];
  v = warpReduceSum(v);
  int wid = threadIdx.x >> 6, lane = threadIdx.x & 63;
  int nw = blockDim.x >> 6;
  if (lane == 0) lds[wid] = v;
  __syncthreads();
  if (wid == 0){
    v = (lane < nw) ? lds[lane] : 0.f;
    #pragma unroll
    for (int m = 4; m; m >>= 1) v += __shfl_xor(v, m);
  }
  __syncthreads();
  return v;  // valid on thread 0
}
__device__ float blockReduceMax(float v){
  __shared__ float lds[8];
  v = warpReduceMax(v);
  int wid = threadIdx.x >> 6, lane = threadIdx.x & 63;
  int nw = blockDim.x >> 6;
  if (lane == 0) lds[wid] = v;
  __syncthreads();
  if (wid == 0){
    v = (lane < nw) ? lds[lane] : -INFINITY;
    #pragma unroll
    for (int m = 4; m; m >>= 1) v = fmaxf(v, __shfl_xor(v, m));
  }
  __syncthreads();
  return v;
}

// ---------- 1. per-channel stats ----------
__global__ __launch_bounds__(256)
void k_stats(const float* __restrict__ S, const float* __restrict__ T,
             float* __restrict__ s_sum, float* __restrict__ s_sq){
  int blk = blockIdx.x;                 // 2*C*B = 4096
  int t = blk / (NC * NBAT);
  int rem = blk % (NC * NBAT);
  int c = rem / NBAT;
  int n = rem % NBAT;
  const float* x = (t ? T : S) + ((size_t)n * NC + c) * NP;
  float s = 0.f, q = 0.f;
  for (int p = threadIdx.x; p < NP; p += 256){ float v = x[p]; s += v; q += v * v; }
  s = blockReduceSum(s);
  q = blockReduceSum(q);
  if (threadIdx.x == 0){
    atomicAdd(&s_sum[t * NC + c], s);
    atomicAdd(&s_sq[t * NC + c], q);
  }
}

__global__ __launch_bounds__(512)
void k_finalize(const float* __restrict__ s_sum, const float* __restrict__ s_sq,
                float* __restrict__ mean, float* __restrict__ inv){
  int i = threadIdx.x;
  if (i < 2 * NC){
    float s = s_sum[i], q = s_sq[i];
    float m = s / (float)NTOT;
    float var = (q - s * m) / (float)(NTOT - 1);
    var = fmaxf(var, 0.f);
    mean[i] = m;
    inv[i] = 1.f / (sqrtf(var) + 1e-6f);
  }
}

// ---------- 2. causal attention ----------
__global__ __launch_bounds__(256)
void k_caM(const float* __restrict__ S, const float* __restrict__ T,
           const float* __restrict__ wcls,
           const float* __restrict__ mean, const float* __restrict__ inv,
           float* __restrict__ smca){
  int pt = blockIdx.x, n = blockIdx.y, t = blockIdx.z;   // (36, 8, 2)
  __shared__ float wsc[NKC * NC];
  __shared__ float shift[NKC];
  for (int idx = threadIdx.x; idx < NKC * NC; idx += 256){
    int c = idx & 255;
    wsc[idx] = wcls[idx] * inv[t * NC + c];
  }
  __syncthreads();
  if (threadIdx.x < NKC){
    float sh = 0.f;
    for (int c = 0; c < NC; c++) sh += wsc[threadIdx.x * NC + c] * mean[t * NC + c];
    shift[threadIdx.x] = sh;
  }
  __syncthreads();
  int p = pt * 256 + threadIdx.x;
  const float* x = (t ? T : S) + (size_t)n * NC * NP + p;
  float acc[NKC];
  #pragma unroll
  for (int k = 0; k < NKC; k++) acc[k] = 0.f;
  for (int c = 0; c < NC; c++){
    float xv = x[(size_t)c * NP];
    #pragma unroll
    for (int k = 0; k < NKC; k++) acc[k] += wsc[k * NC + c] * xv;
  }
  size_t base = ((size_t)(t * NBAT + n) * NKC) * NP + p;
  #pragma unroll
  for (int k = 0; k < NKC; k++) smca[base + (size_t)k * NP] = acc[k] - shift[k];
}

__global__ __launch_bounds__(256)
void k_caSoftmax(float* __restrict__ smca){
  int r = blockIdx.x;                      // 96 rows
  float* row = smca + (size_t)r * NP;
  float m = -INFINITY;
  for (int p = threadIdx.x; p < NP; p += 256) m = fmaxf(m, row[p]);
  m = blockReduceMax(m);
  __shared__ float bm, bs;
  if (threadIdx.x == 0) bm = m;
  __syncthreads();
  m = bm;
  float s = 0.f;
  for (int p = threadIdx.x; p < NP; p += 256) s += expf(row[p] - m);
  s = blockReduceSum(s);
  if (threadIdx.x == 0) bs = 1.f / s;
  __syncthreads();
  float rs = bs;
  for (int p = threadIdx.x; p < NP; p += 256) row[p] = expf(row[p] - m) * rs;
}

__global__ __launch_bounds__(256)
void k_caOut(const float* __restrict__ S, const float* __restrict__ T,
             const float* __restrict__ smca,
             const float* __restrict__ mean, const float* __restrict__ inv,
             float* __restrict__ ca){
  int ct = blockIdx.x, n = blockIdx.y, t = blockIdx.z;   // (8, 8, 2)
  int c0 = ct * 32;
  __shared__ float xt[32 * 264];
  __shared__ float smt[NKC * 256];
  int cl = threadIdx.x >> 3, pl = threadIdx.x & 7;
  float acc[NKC];
  #pragma unroll
  for (int k = 0; k < NKC; k++) acc[k] = 0.f;
  const float* xbase = (t ? T : S) + (size_t)n * NC * NP;
  const float* smbase = smca + (size_t)(t * NBAT + n) * NKC * NP;
  for (int pt = 0; pt < 36; pt++){
    int p0 = pt * 256;
    for (int idx = threadIdx.x; idx < 32 * 256; idx += 256){
      int r = idx >> 8, p = idx & 255;
      float v = xbase[(size_t)(c0 + r) * NP + p0 + p];
      xt[r * 264 + p] = (v - mean[t * NC + c0 + r]) * inv[t * NC + c0 + r];
    }
    for (int idx = threadIdx.x; idx < NKC * 256; idx += 256){
      int k = idx >> 8, p = idx & 255;
      smt[idx] = smbase[(size_t)k * NP + p0 + p];
    }
    __syncthreads();
    for (int j = 0; j < 32; j++){
      float xv = xt[cl * 264 + pl + 8 * j];
      #pragma unroll
      for (int k = 0; k < NKC; k++) acc[k] += smt[k * 256 + pl + 8 * j] * xv;
    }
    __syncthreads();
  }
  #pragma unroll
  for (int k = 0; k < NKC; k++){
    float v = acc[k];
    v += __shfl_xor(v, 1); v += __shfl_xor(v, 2); v += __shfl_xor(v, 4);
    if (pl == 0) ca[((size_t)(t * NBAT + n) * NKC + k) * NC + c0 + cl] = v;
  }
}

__global__ __launch_bounds__(256)
void k_caLoss(const float* __restrict__ ca, float* __restrict__ out){
  int i = blockIdx.x * 256 + threadIdx.x;   // 12288 total
  float d = 0.f;
  if (i < NBAT * NKC * NC) d = ca[(size_t)NBAT * NKC * NC + i] - ca[i];
  float ss = blockReduceSum(d * d);
  if (threadIdx.x == 0) atomicAdd(out, ss * (0.0005f / 8.0f));
}

// ---------- 3. q/k GEMM: [64 x 9216] = W[64 x 256] @ xn[256 x 9216] ----------
__global__ __launch_bounds__(256)
void k_qk(const float* __restrict__ x0, int b0,
          const float* __restrict__ wq, const float* __restrict__ bq,
          const float* __restrict__ wk, const float* __restrict__ bk,
          const float* __restrict__ mean, const float* __restrict__ inv, int t,
          float* __restrict__ qbuf, float* __restrict__ kbuf){
  int pt = blockIdx.x, bb = blockIdx.y;     // (144, NB)
  int bg = b0 + bb;
  const float* x = x0 + (size_t)bg * NC * NP;
  int p0 = pt * 64;
  __shared__ float Al[64 * 33];
  __shared__ float Bl[32 * 68];
  int tx = threadIdx.x & 15, ty = threadIdx.x >> 4;
  float acc[4][4] = {};
  for (int kk = 0; kk < NC; kk += 32){
    for (int idx = threadIdx.x; idx < 64 * 32; idx += 256){
      int r = idx >> 5, cc = idx & 31;
      float w = (r < 32) ? wq[r * NC + kk + cc] : wk[(r - 32) * NC + kk + cc];
      Al[r * 33 + cc] = w;
    }
    for (int idx = threadIdx.x; idx < 32 * 64; idx += 256){
      int r = idx >> 6, pl = idx & 63;
      float v = x[(size_t)(kk + r) * NP + p0 + pl];
      Bl[r * 68 + pl] = (v - mean[t * NC + kk + r]) * inv[t * NC + kk + r];
    }
    __syncthreads();
    #pragma unroll 8
    for (int k = 0; k < 32; k++){
      float a[4], b[4];
      #pragma unroll
      for (int i = 0; i < 4; i++) a[i] = Al[(ty * 4 + i) * 33 + k];
      #pragma unroll
      for (int j = 0; j < 4; j++) b[j] = Bl[k * 68 + tx * 4 + j];
      #pragma unroll
      for (int i = 0; i < 4; i++)
        #pragma unroll
        for (int j = 0; j < 4; j++) acc[i][j] = fmaf(a[i], b[j], acc[i][j]);
    }
    __syncthreads();
  }
  #pragma unroll
  for (int i = 0; i < 4; i++){
    int m = ty * 4 + i;
    float bias = (m < 32) ? bq[m] : bk[m - 32];
    float* dst = (m < 32) ? qbuf : kbuf;
    int mo = (m < 32) ? m : m - 32;
    #pragma unroll
    for (int j = 0; j < 4; j++){
      int p = p0 + tx * 4 + j;
      dst[((size_t)bb * NP + p) * NCQ + mo] = acc[i][j] + bias;
    }
  }
}

// ---------- 4. v GEMM: v[256 x 9216] -> VT[b][w][h][c] (bf16) ----------
__global__ __launch_bounds__(256)
void k_v(const float* __restrict__ x0, int b0,
         const float* __restrict__ wv, const float* __restrict__ bv,
         const float* __restrict__ mean, const float* __restrict__ inv, int t,
         unsigned short* __restrict__ VT){
  int mt = blockIdx.x, pt = blockIdx.y, bb = blockIdx.z;  // (4, 144, NB)
  int bg = b0 + bb;
  const float* x = x0 + (size_t)bg * NC * NP;
  int p0 = pt * 64;
  __shared__ float Al[64 * 33];
  __shared__ float Bl[32 * 68];
  int tx = threadIdx.x & 15, ty = threadIdx.x >> 4;
  float acc[4][4] = {};
  for (int kk = 0; kk < NC; kk += 32){
    for (int idx = threadIdx.x; idx < 64 * 32; idx += 256){
      int r = idx >> 5, cc = idx & 31;
      Al[r * 33 + cc] = wv[(size_t)(mt * 64 + r) * NC + kk + cc];
    }
    for (int idx = threadIdx.x; idx < 32 * 64; idx += 256){
      int r = idx >> 6, pl = idx & 63;
      float v = x[(size_t)(kk + r) * NP + p0 + pl];
      Bl[r * 68 + pl] = (v - mean[t * NC + kk + r]) * inv[t * NC + kk + r];
    }
    __syncthreads();
    #pragma unroll 8
    for (int k = 0; k < 32; k++){
      float a[4], b[4];
      #pragma unroll
      for (int i = 0; i < 4; i++) a[i] = Al[(ty * 4 + i) * 33 + k];
      #pragma unroll
      for (int j = 0; j < 4; j++) b[j] = Bl[k * 68 + tx * 4 + j];
      #pragma unroll
      for (int i = 0; i < 4; i++)
        #pragma unroll
        for (int j = 0; j < 4; j++) acc[i][j] = fmaf(a[i], b[j], acc[i][j]);
    }
    __syncthreads();
  }
  #pragma unroll
  for (int i = 0; i < 4; i++){
    int m = mt * 64 + ty * 4 + i;
    float bias = bv[m];
    #pragma unroll
    for (int j = 0; j < 4; j++){
      int p = p0 + tx * 4 + j;
      int hh = p / 96, ww = p % 96;
      VT[(((size_t)bb * 96 + ww) * 96 + hh) * NC + m] = f2bf(acc[i][j] + bias);
    }
  }
}

// ---------- 5. eH scores (diag masked): att[b][ih*96+w][j], j<96 ----------
__global__ __launch_bounds__(256)
void k_eH(const float* __restrict__ qbuf, const float* __restrict__ kbuf,
          unsigned short* __restrict__ att){
  int w = blockIdx.x, bb = blockIdx.y;      // (96, NB)
  __shared__ float ql[96 * 33], kl[96 * 33];
  for (int idx = threadIdx.x; idx < 96 * 32; idx += 256){
    int r = idx >> 5, cq = idx & 31;
    size_t src = ((size_t)bb * NP + (r * 96 + w)) * NCQ + cq;
    ql[r * 33 + cq] = qbuf[src];
    kl[r * 33 + cq] = kbuf[src];
  }
  __syncthreads();
  int tx = threadIdx.x & 15, ty = threadIdx.x >> 4;
  int i0 = ty * 6, j0 = tx * 6;
  float acc[6][6] = {};
  for (int c = 0; c < 32; c++){
    float a[6], b[6];
    #pragma unroll
    for (int i = 0; i < 6; i++) a[i] = ql[(i0 + i) * 33 + c];
    #pragma unroll
    for (int j = 0; j < 6; j++) b[j] = kl[(j0 + j) * 33 + c];
    #pragma unroll
    for (int i = 0; i < 6; i++)
      #pragma unroll
      for (int j = 0; j < 6; j++) acc[i][j] = fmaf(a[i], b[j], acc[i][j]);
  }
  #pragma unroll
  for (int i = 0; i < 6; i++){
    int ih = i0 + i;
    size_t rowbase = ((size_t)bb * NP + (ih * 96 + w)) * NL;
    #pragma unroll
    for (int j = 0; j < 6; j++){
      int jh = j0 + j;
      float v = (jh == ih) ? -INFINITY : acc[i][j];
      att[rowbase + jh] = f2bf(v);
    }
  }
}

// ---------- 6. eW scores: att[b][h*96+i][96+j] ----------
__global__ __launch_bounds__(256)
void k_eW(const float* __restrict__ qbuf, const float* __restrict__ kbuf,
          unsigned short* __restrict__ att){
  int h = blockIdx.x, bb = blockIdx.y;      // (96, NB)
  __shared__ float ql[96 * 33], kl[96 * 33];
  for (int idx = threadIdx.x; idx < 96 * 32; idx += 256){
    int r = idx >> 5, cq = idx & 31;
    size_t src = ((size_t)bb * NP + (h * 96 + r)) * NCQ + cq;
    ql[r * 33 + cq] = qbuf[src];
    kl[r * 33 + cq] = kbuf[src];
  }
  __syncthreads();
  int tx = threadIdx.x & 15, ty = threadIdx.x >> 4;
  int i0 = ty * 6, j0 = tx * 6;
  float acc[6][6] = {};
  for (int c = 0; c < 32; c++){
    float a[6], b[6];
    #pragma unroll
    for (int i = 0; i < 6; i++) a[i] = ql[(i0 + i) * 33 + c];
    #pragma unroll
    for (int j = 0; j < 6; j++) b[j] = kl[(j0 + j) * 33 + c];
    #pragma unroll
    for (int i = 0; i < 6; i++)
      #pragma unroll
      for (int j = 0; j < 6; j++) acc[i][j] = fmaf(a[i], b[j], acc[i][j]);
  }
  #pragma unroll
  for (int i = 0; i < 6; i++){
    size_t rowbase = ((size_t)bb * NP + (h * 96 + i0 + i)) * NL + 96;
    #pragma unroll
    for (int j = 0; j < 6; j++) att[rowbase + j0 + j] = f2bf(acc[i][j]);
  }
}

// ---------- 7. softmax over 192 per query ----------
__global__ __launch_bounds__(256)
void k_attSoftmax(unsigned short* __restrict__ att){
  int q = blockIdx.x * 4 + (threadIdx.x >> 6);
  int lane = threadIdx.x & 63;
  unsigned short* row = att + (size_t)q * NL;
  float e0 = bf2f(row[lane]);
  float e1 = bf2f(row[64 + lane]);
  float e2 = bf2f(row[128 + lane]);
  float m = fmaxf(e0, fmaxf(e1, e2));
  m = warpReduceMax(m);
  float x0 = expf(e0 - m), x1 = expf(e1 - m), x2 = expf(e2 - m);
  float s = warpReduceSum(x0 + x1 + x2);
  float rs = 1.f / s;
  row[lane]       = f2bf(x0 * rs);
  row[64 + lane]  = f2bf(x1 * rs);
  row[128 + lane] = f2bf(x2 * rs);
}

// ---------- 8. outH: OHt[b][w][ih][c] = sum_j attH[(ih,w),j] * VT[b][w][j][c] ----------
__global__ __launch_bounds__(128)
void k_outH(const unsigned short* __restrict__ VT, const unsigned short* __restrict__ att,
            unsigned short* __restrict__ OHt){
  int iq = blockIdx.x, w = blockIdx.y, bb = blockIdx.z;  // (4, 96, NB)
  __shared__ float al[96 * 28];
  for (int idx = threadIdx.x; idx < 24 * 96; idx += 128){
    int ii = idx / 96, j = idx % 96;
    al[j * 28 + ii] = bf2f(att[((size_t)bb * NP + ((iq * 24 + ii) * 96 + w)) * NL + j]);
  }
  __syncthreads();
  int c0 = threadIdx.x * 2;
  float acc[24][2] = {};
  for (int j = 0; j < 96; j++){
    unsigned uv = *(const unsigned*)(VT + (((size_t)bb * 96 + w) * 96 + j) * NC + c0);
    float v0 = bflo(uv), v1 = bfhi(uv);
    #pragma unroll
    for (int ic = 0; ic < 6; ic++){
      F4 a; a.v = *(const float4*)(al + j * 28 + ic * 4);
      #pragma unroll
      for (int r = 0; r < 4; r++){
        acc[ic * 4 + r][0] = fmaf(a.a[r], v0, acc[ic * 4 + r][0]);
        acc[ic * 4 + r][1] = fmaf(a.a[r], v1, acc[ic * 4 + r][1]);
      }
    }
  }
  #pragma unroll
  for (int ii = 0; ii < 24; ii++){
    size_t base = (((size_t)bb * 96 + w) * 96 + (iq * 24 + ii)) * NC + c0;
    unsigned outp = (unsigned)f2bf(acc[ii][0]) | ((unsigned)f2bf(acc[ii][1]) << 16);
    *(unsigned*)(OHt + base) = outp;
  }
}

// ---------- 9. outW + total O; T pass stores Ot; S pass fuses loss ----------
__global__ __launch_bounds__(128)
void k_outW(const unsigned short* __restrict__ VT, const unsigned short* __restrict__ att,
            const unsigned short* __restrict__ OHt, unsigned short* __restrict__ Ot,
            const float* __restrict__ predsS, const float* __restrict__ predsT,
            const float* __restrict__ mean, const float* __restrict__ inv,
            const float* __restrict__ gamma, int b0, int spass,
            float* __restrict__ out){
  int iq = blockIdx.x, h = blockIdx.y, bb = blockIdx.z;  // (4, 96, NB)
  __shared__ float al[96 * 28];
  for (int idx = threadIdx.x; idx < 24 * 96; idx += 128){
    int ii = idx / 96, j = idx % 96;
    al[j * 28 + ii] = bf2f(att[((size_t)bb * NP + (h * 96 + (iq * 24 + ii))) * NL + 96 + j]);
  }
  __syncthreads();
  int c0 = threadIdx.x * 2;
  float acc[24][2] = {};
  for (int j = 0; j < 96; j++){
    unsigned uv = *(const unsigned*)(VT + (((size_t)bb * 96 + j) * 96 + h) * NC + c0);
    float v0 = bflo(uv), v1 = bfhi(uv);
    #pragma unroll
    for (int ic = 0; ic < 6; ic++){
      F4 a; a.v = *(const float4*)(al + j * 28 + ic * 4);
      #pragma unroll
      for (int r = 0; r < 4; r++){
        acc[ic * 4 + r][0] = fmaf(a.a[r], v0, acc[ic * 4 + r][0]);
        acc[ic * 4 + r][1] = fmaf(a.a[r], v1, acc[ic * 4 + r][1]);
      }
    }
  }
  if (!spass){
    // T pass: Ot = outH + outW (transposed layout, bf16)
    #pragma unroll
    for (int ii = 0; ii < 24; ii++){
      int i = iq * 24 + ii;
      size_t base = (((size_t)bb * 96 + i) * 96 + h) * NC + c0;
      unsigned uoh = *(const unsigned*)(OHt + base);
      float t0 = acc[ii][0] + bflo(uoh);
      float t1 = acc[ii][1] + bfhi(uoh);
      unsigned outp = (unsigned)f2bf(t0) | ((unsigned)f2bf(t1) << 16);
    *(unsigned*)(Ot + base) = outp;
    }
  } else {
    // S pass: d = gamma*(O_t - O_s) + (t_n - s_n); accumulate d^2
    int bg = b0 + bb;
    float g = gamma[0];
    int c1 = c0 + 1;
    float mS0 = mean[c0],      iS0 = inv[c0];
    float mS1 = mean[c1],      iS1 = inv[c1];
    float mT0 = mean[NC + c0], iT0 = inv[NC + c0];
    float mT1 = mean[NC + c1], iT1 = inv[NC + c1];
    const float* tp0 = predsT + ((size_t)bg * NC + c0) * NP + h * 96;
    const float* tp1 = predsT + ((size_t)bg * NC + c1) * NP + h * 96;
    const float* sp0 = predsS + ((size_t)bg * NC + c0) * NP + h * 96;
    const float* sp1 = predsS + ((size_t)bg * NC + c1) * NP + h * 96;
    float ss = 0.f;
    #pragma unroll
    for (int ic = 0; ic < 6; ic++){
      int ib = iq * 24 + ic * 4;
      F4 tA, tB, sA, sB;
      tA.v = *(const float4*)(tp0 + ib);
      tB.v = *(const float4*)(tp1 + ib);
      sA.v = *(const float4*)(sp0 + ib);
      sB.v = *(const float4*)(sp1 + ib);
      #pragma unroll
      for (int r = 0; r < 4; r++){
        int ii = ic * 4 + r;
        int i = ib + r;
        size_t base = (((size_t)bb * 96 + i) * 96 + h) * NC + c0;
        unsigned uoh = *(const unsigned*)(OHt + base);
        unsigned uot = *(const unsigned*)(Ot + base);
        float os0 = acc[ii][0] + bflo(uoh);
        float os1 = acc[ii][1] + bfhi(uoh);
        float dn0 = (tA.a[r] - mT0) * iT0 - (sA.a[r] - mS0) * iS0;
        float dn1 = (tB.a[r] - mT1) * iT1 - (sB.a[r] - mS1) * iS1;
        float d0 = g * (bflo(uot) - os0) + dn0;
        float d1 = g * (bfhi(uot) - os1) + dn1;
        ss += d0 * d0 + d1 * d1;
      }
    }
    ss = blockReduceSum(ss);
    if (threadIdx.x == 0) atomicAdd(out, ss * (1e-5f / 8.0f));
  }
}

// ---------- host ----------
extern "C" void kernel_launch(void* const* d_in, const int* in_sizes, int n_in,
                              void* d_out, int out_size, void* d_ws, size_t ws_size,
                              hipStream_t stream){
  (void)in_sizes; (void)n_in; (void)out_size;
  const float* S    = (const float*)d_in[0];
  const float* T    = (const float*)d_in[1];
  const float* wcls = (const float*)d_in[2];
  const float* wq   = (const float*)d_in[3];
  const float* bq   = (const float*)d_in[4];
  const float* wk   = (const float*)d_in[5];
  const float* bk   = (const float*)d_in[6];
  const float* wv   = (const float*)d_in[7];
  const float* bv   = (const float*)d_in[8];
  const float* gamma= (const float*)d_in[9];
  float* out = (float*)d_out;

  char* base = (char*)d_ws;
  size_t off = 0;
  auto alloc = [&](size_t b){ size_t o = off; off += (b + 255) & ~(size_t)255; return o; };
  size_t o_ssum = alloc(2 * NC * 4);
  size_t o_ssq  = alloc(2 * NC * 4);
  size_t o_mean = alloc(2 * NC * 4);
  size_t o_inv  = alloc(2 * NC * 4);
  size_t o_ca   = alloc((size_t)2 * NBAT * NKC * NC * 4);
  size_t o_smca = alloc((size_t)2 * NBAT * NKC * NP * 4);
  size_t fixed = off;
  size_t per_b = (size_t)NP * NCQ * 4 * 2      // q + k (fp32)
               + (size_t)NP * NC * 2 * 3       // VT + OHt + Ot (bf16)
               + (size_t)NP * NL * 2;          // att (bf16)
  int NB = 8;
  while (NB > 1 && fixed + (size_t)NB * per_b + 8192 > ws_size) NB >>= 1;

  size_t o_q   = alloc((size_t)NB * NP * NCQ * 4);
  size_t o_k   = alloc((size_t)NB * NP * NCQ * 4);
  size_t o_vt  = alloc((size_t)NB * NP * NC * 2);
  size_t o_att = alloc((size_t)NB * NP * NL * 2);
  size_t o_oh  = alloc((size_t)NB * NP * NC * 2);
  size_t o_ot  = alloc((size_t)NB * NP * NC * 2);

  float* ssum = (float*)(base + o_ssum);
  float* ssq  = (float*)(base + o_ssq);
  float* mean = (float*)(base + o_mean);
  float* inv  = (float*)(base + o_inv);
  float* ca   = (float*)(base + o_ca);
  float* smca = (float*)(base + o_smca);
  float* qb   = (float*)(base + o_q);
  float* kb   = (float*)(base + o_k);
  unsigned short* VT  = (unsigned short*)(base + o_vt);
  unsigned short* att = (unsigned short*)(base + o_att);
  unsigned short* OHt = (unsigned short*)(base + o_oh);
  unsigned short* Ot  = (unsigned short*)(base + o_ot);

  hipMemsetAsync(d_out, 0, 4, stream);
  hipMemsetAsync(base + o_ssum, 0, 4096, stream);

  k_stats<<<dim3(2 * NC * NBAT), 256, 0, stream>>>(S, T, ssum, ssq);
  k_finalize<<<1, 512, 0, stream>>>(ssum, ssq, mean, inv);

  // causal attention (both tensors, full batch)
  k_caM<<<dim3(36, NBAT, 2), 256, 0, stream>>>(S, T, wcls, mean, inv, smca);
  k_caSoftmax<<<dim3(2 * NBAT * NKC), 256, 0, stream>>>(smca);
  k_caOut<<<dim3(8, NBAT, 2), 256, 0, stream>>>(S, T, smca, mean, inv, ca);
  k_caLoss<<<dim3(48), 256, 0, stream>>>(ca, out);

  // ccnet: per batch-chunk, tensor T then S (loss fused into S outW)
  for (int b0 = 0; b0 < NBAT; b0 += NB){
    for (int pass = 0; pass < 2; pass++){
      int t = (pass == 0) ? 1 : 0;
      const float* x = t ? T : S;
      k_qk<<<dim3(144, NB), 256, 0, stream>>>(x, b0, wq, bq, wk, bk, mean, inv, t, qb, kb);
      k_v<<<dim3(4, 144, NB), 256, 0, stream>>>(x, b0, wv, bv, mean, inv, t, VT);
      k_eH<<<dim3(96, NB), 256, 0, stream>>>(qb, kb, att);
      k_eW<<<dim3(96, NB), 256, 0, stream>>>(qb, kb, att);
      k_attSoftmax<<<dim3(NB * 2304), 256, 0, stream>>>(att);
      k_outH<<<dim3(4, 96, NB), 128, 0, stream>>>(VT, att, OHt);
      k_outW<<<dim3(4, 96, NB), 128, 0, stream>>>(VT, att, OHt, Ot, S, T, mean, inv,
                                                  gamma, b0, pass, out);
    }
  }
}

// Round 2
// 921.394 us; speedup vs baseline: 1.6708x; 1.6708x over previous
//
#include <hip/hip_runtime.h>
#include <math.h>

#define NBAT 8
#define NC   256
#define NH   96
#define NW   96
#define NP   9216
#define NCQ  32
#define NKC  6
#define NL   192
#define NV   320          // 256 v-channels + 32 q + 32 k
#define NTOT 73728        // NBAT*NP

typedef __attribute__((ext_vector_type(4))) float  floatx4;
typedef __attribute__((ext_vector_type(8))) short  short8;

// ---------- bf16 helpers (storage only; math fp32) ----------
__device__ __forceinline__ float bf2f(unsigned short h){
  return __uint_as_float(((unsigned)h) << 16);
}
__device__ __forceinline__ float bflo(unsigned u){ return __uint_as_float(u << 16); }
__device__ __forceinline__ float bfhi(unsigned u){ return __uint_as_float(u & 0xFFFF0000u); }
__device__ __forceinline__ unsigned short f2bf(float f){
  unsigned u = __float_as_uint(f);
  u += 0x7FFFu + ((u >> 16) & 1u);
  return (unsigned short)(u >> 16);
}

union F4 { float4 v; float a[4]; };

// ---------- reductions ----------
__device__ __forceinline__ float warpReduceSum(float v){
  #pragma unroll
  for (int m = 32; m; m >>= 1) v += __shfl_xor(v, m);
  return v;
}
__device__ __forceinline__ float warpReduceMax(float v){
  #pragma unroll
  for (int m = 32; m; m >>= 1) v = fmaxf(v, __shfl_xor(v, m));
  return v;
}
__device__ float blockReduceSum(float v){
  __shared__ float lds[8];
  v = warpReduceSum(v);
  int wid = threadIdx.x >> 6, lane = threadIdx.x & 63;
  int nw = blockDim.x >> 6;
  if (lane == 0) lds[wid] = v;
  __syncthreads();
  if (wid == 0){
    v = (lane < nw) ? lds[lane] : 0.f;
    #pragma unroll
    for (int m = 4; m; m >>= 1) v += __shfl_xor(v, m);
  }
  __syncthreads();
  return v;  // valid on thread 0
}
__device__ float blockReduceMax(float v){
  __shared__ float lds[8];
  v = warpReduceMax(v);
  int wid = threadIdx.x >> 6, lane = threadIdx.x & 63;
  int nw = blockDim.x >> 6;
  if (lane == 0) lds[wid] = v;
  __syncthreads();
  if (wid == 0){
    v = (lane < nw) ? lds[lane] : -INFINITY;
    #pragma unroll
    for (int m = 4; m; m >>= 1) v = fmaxf(v, __shfl_xor(v, m));
  }
  __syncthreads();
  return v;
}

// ---------- 1. per-channel stats ----------
__global__ __launch_bounds__(256)
void k_stats(const float* __restrict__ S, const float* __restrict__ T,
             float* __restrict__ s_sum, float* __restrict__ s_sq){
  int blk = blockIdx.x;                 // 2*C*B = 4096
  int t = blk / (NC * NBAT);
  int rem = blk % (NC * NBAT);
  int c = rem / NBAT;
  int n = rem % NBAT;
  const float* x = (t ? T : S) + ((size_t)n * NC + c) * NP;
  float s = 0.f, q = 0.f;
  for (int p = threadIdx.x; p < NP; p += 256){ float v = x[p]; s += v; q += v * v; }
  s = blockReduceSum(s);
  q = blockReduceSum(q);
  if (threadIdx.x == 0){
    atomicAdd(&s_sum[t * NC + c], s);
    atomicAdd(&s_sq[t * NC + c], q);
  }
}

__global__ __launch_bounds__(512)
void k_finalize(const float* __restrict__ s_sum, const float* __restrict__ s_sq,
                float* __restrict__ mean, float* __restrict__ inv){
  int i = threadIdx.x;
  if (i < 2 * NC){
    float s = s_sum[i], q = s_sq[i];
    float m = s / (float)NTOT;
    float var = (q - s * m) / (float)(NTOT - 1);
    var = fmaxf(var, 0.f);
    mean[i] = m;
    inv[i] = 1.f / (sqrtf(var) + 1e-6f);
  }
}

// ---------- 2. causal attention ----------
__global__ __launch_bounds__(256)
void k_caM(const float* __restrict__ S, const float* __restrict__ T,
           const float* __restrict__ wcls,
           const float* __restrict__ mean, const float* __restrict__ inv,
           float* __restrict__ smca){
  int pt = blockIdx.x, n = blockIdx.y, t = blockIdx.z;   // (36, 8, 2)
  __shared__ float wsc[NKC * NC];
  __shared__ float shift[NKC];
  for (int idx = threadIdx.x; idx < NKC * NC; idx += 256){
    int c = idx & 255;
    wsc[idx] = wcls[idx] * inv[t * NC + c];
  }
  __syncthreads();
  if (threadIdx.x < NKC){
    float sh = 0.f;
    for (int c = 0; c < NC; c++) sh += wsc[threadIdx.x * NC + c] * mean[t * NC + c];
    shift[threadIdx.x] = sh;
  }
  __syncthreads();
  int p = pt * 256 + threadIdx.x;
  const float* x = (t ? T : S) + (size_t)n * NC * NP + p;
  float acc[NKC];
  #pragma unroll
  for (int k = 0; k < NKC; k++) acc[k] = 0.f;
  for (int c = 0; c < NC; c++){
    float xv = x[(size_t)c * NP];
    #pragma unroll
    for (int k = 0; k < NKC; k++) acc[k] += wsc[k * NC + c] * xv;
  }
  size_t base = ((size_t)(t * NBAT + n) * NKC) * NP + p;
  #pragma unroll
  for (int k = 0; k < NKC; k++) smca[base + (size_t)k * NP] = acc[k] - shift[k];
}

__global__ __launch_bounds__(256)
void k_caSoftmax(float* __restrict__ smca){
  int r = blockIdx.x;                      // 96 rows
  float* row = smca + (size_t)r * NP;
  float m = -INFINITY;
  for (int p = threadIdx.x; p < NP; p += 256) m = fmaxf(m, row[p]);
  m = blockReduceMax(m);
  __shared__ float bm, bs;
  if (threadIdx.x == 0) bm = m;
  __syncthreads();
  m = bm;
  float s = 0.f;
  for (int p = threadIdx.x; p < NP; p += 256) s += expf(row[p] - m);
  s = blockReduceSum(s);
  if (threadIdx.x == 0) bs = 1.f / s;
  __syncthreads();
  float rs = bs;
  for (int p = threadIdx.x; p < NP; p += 256) row[p] = expf(row[p] - m) * rs;
}

// split-K caOut: grid.x = ct(8) + 8*ks(6) — each block does 6 p-tiles, atomicAdd out
__global__ __launch_bounds__(256)
void k_caOut(const float* __restrict__ S, const float* __restrict__ T,
             const float* __restrict__ smca,
             const float* __restrict__ mean, const float* __restrict__ inv,
             float* __restrict__ ca){
  int ct = blockIdx.x & 7, ks = blockIdx.x >> 3;
  int n = blockIdx.y, t = blockIdx.z;   // (48, 8, 2)
  int c0 = ct * 32;
  __shared__ float xt[32 * 264];
  __shared__ float smt[NKC * 256];
  int cl = threadIdx.x >> 3, pl = threadIdx.x & 7;
  float acc[NKC];
  #pragma unroll
  for (int k = 0; k < NKC; k++) acc[k] = 0.f;
  const float* xbase = (t ? T : S) + (size_t)n * NC * NP;
  const float* smbase = smca + (size_t)(t * NBAT + n) * NKC * NP;
  for (int pt = ks * 6; pt < ks * 6 + 6; pt++){
    int p0 = pt * 256;
    for (int idx = threadIdx.x; idx < 32 * 256; idx += 256){
      int r = idx >> 8, p = idx & 255;
      float v = xbase[(size_t)(c0 + r) * NP + p0 + p];
      xt[r * 264 + p] = (v - mean[t * NC + c0 + r]) * inv[t * NC + c0 + r];
    }
    for (int idx = threadIdx.x; idx < NKC * 256; idx += 256){
      int k = idx >> 8, p = idx & 255;
      smt[idx] = smbase[(size_t)k * NP + p0 + p];
    }
    __syncthreads();
    for (int j = 0; j < 32; j++){
      float xv = xt[cl * 264 + pl + 8 * j];
      #pragma unroll
      for (int k = 0; k < NKC; k++) acc[k] += smt[k * 256 + pl + 8 * j] * xv;
    }
    __syncthreads();
  }
  #pragma unroll
  for (int k = 0; k < NKC; k++){
    float v = acc[k];
    v += __shfl_xor(v, 1); v += __shfl_xor(v, 2); v += __shfl_xor(v, 4);
    if (pl == 0) atomicAdd(&ca[((size_t)(t * NBAT + n) * NKC + k) * NC + c0 + cl], v);
  }
}

__global__ __launch_bounds__(256)
void k_caLoss(const float* __restrict__ ca, float* __restrict__ out){
  int i = blockIdx.x * 256 + threadIdx.x;   // 12288 total
  float d = 0.f;
  if (i < NBAT * NKC * NC) d = ca[(size_t)NBAT * NKC * NC + i] - ca[i];
  float ss = blockReduceSum(d * d);
  if (threadIdx.x == 0) atomicAdd(out, ss * (0.0005f / 8.0f));
}

// ---------- 3. stage normalized x as bf16 XN[b][p][c] (transpose) ----------
__global__ __launch_bounds__(256)
void k_xn(const float* __restrict__ x0, int b0,
          const float* __restrict__ mean, const float* __restrict__ inv, int t,
          unsigned short* __restrict__ XN){
  int pt = blockIdx.x, ct = blockIdx.y, bb = blockIdx.z;  // (144, 4, NB)
  int bg = b0 + bb;
  int p0 = pt * 64, c0 = ct * 64;
  __shared__ float tile[64 * 65];
  const float* x = x0 + ((size_t)bg * NC + c0) * NP + p0;
  #pragma unroll
  for (int i = 0; i < 4; i++){
    int idx = threadIdx.x + i * 256;       // 64 c-rows x 16 float4 groups
    int r = idx >> 4, g = (idx & 15) * 4;
    F4 f; f.v = *(const float4*)(x + (size_t)r * NP + g);
    float m = mean[t * NC + c0 + r], iv = inv[t * NC + c0 + r];
    #pragma unroll
    for (int j = 0; j < 4; j++) tile[(g + j) * 65 + r] = (f.a[j] - m) * iv;
  }
  __syncthreads();
  #pragma unroll
  for (int i = 0; i < 4; i++){
    int idx = threadIdx.x + i * 256;       // 64 p-rows x 16 groups of 4c
    int p = idx >> 4, g = (idx & 15) * 4;
    unsigned lo = (unsigned)f2bf(tile[p * 65 + g + 0]) | ((unsigned)f2bf(tile[p * 65 + g + 1]) << 16);
    unsigned hi = (unsigned)f2bf(tile[p * 65 + g + 2]) | ((unsigned)f2bf(tile[p * 65 + g + 3]) << 16);
    uint2 u; u.x = lo; u.y = hi;
    *(uint2*)(XN + ((size_t)bb * NP + p0 + p) * NC + c0 + g) = u;
  }
}

// ---------- 4. MFMA GEMM: [p x 320] = XN[p x 256] @ W^T; n<256 -> V, then q, k ----------
__global__ __launch_bounds__(256)
void k_v(const unsigned short* __restrict__ XN,
         const float* __restrict__ wv, const float* __restrict__ bv,
         const float* __restrict__ wq, const float* __restrict__ bq,
         const float* __restrict__ wk, const float* __restrict__ bk,
         unsigned short* __restrict__ V,
         unsigned short* __restrict__ qb, unsigned short* __restrict__ kb){
  int pt = blockIdx.x, bb = blockIdx.y;   // (144, NB)
  int p0 = pt * 64;
  __shared__ unsigned short Wl[NV * 40];  // stride 40 shorts: 16B-aligned rows, 2-way banks max
  int lane = threadIdx.x & 63;
  int wid = threadIdx.x >> 6;
  int col = lane & 15, quad = lane >> 4;
  const unsigned short* xnb = XN + (size_t)bb * NP * NC;
  floatx4 acc[20];
  #pragma unroll
  for (int nt = 0; nt < 20; nt++) acc[nt] = (floatx4){0.f, 0.f, 0.f, 0.f};

  for (int ks = 0; ks < 8; ks++){
    int k0 = ks * 32;
    // stage W (v|q|k) as bf16 into LDS
    for (int n = threadIdx.x; n < NV; n += 256){
      const float* src = (n < 256) ? (wv + (size_t)n * NC + k0)
                       : (n < 288) ? (wq + (size_t)(n - 256) * NC + k0)
                                   : (wk + (size_t)(n - 288) * NC + k0);
      unsigned short* dst = Wl + n * 40;
      #pragma unroll
      for (int i = 0; i < 8; i++){
        F4 f; f.v = *(const float4*)(src + i * 4);
        dst[i * 4 + 0] = f2bf(f.a[0]);
        dst[i * 4 + 1] = f2bf(f.a[1]);
        dst[i * 4 + 2] = f2bf(f.a[2]);
        dst[i * 4 + 3] = f2bf(f.a[3]);
      }
    }
    __syncthreads();
    // A-frag: lane holds A[m=lane&15][k=quad*8+j], direct from global
    short8 a = *(const short8*)(xnb + (size_t)(p0 + wid * 16 + col) * NC + k0 + quad * 8);
    #pragma unroll
    for (int nt = 0; nt < 20; nt++){
      short8 b = *(const short8*)(Wl + (nt * 16 + col) * 40 + quad * 8);
      acc[nt] = __builtin_amdgcn_mfma_f32_16x16x32_bf16(a, b, acc[nt], 0, 0, 0);
    }
    __syncthreads();
  }

  // epilogue: D row=(quad*4+i), col=(lane&15) within each 16x16 tile
  int prow0 = p0 + wid * 16 + quad * 4;
  #pragma unroll
  for (int nt = 0; nt < 16; nt++){
    int c = nt * 16 + col;
    float bias = bv[c];
    #pragma unroll
    for (int i = 0; i < 4; i++)
      V[((size_t)bb * NP + prow0 + i) * NC + c] = f2bf(acc[nt][i] + bias);
  }
  #pragma unroll
  for (int nt = 16; nt < 18; nt++){
    int c = (nt - 16) * 16 + col;
    float bias = bq[c];
    #pragma unroll
    for (int i = 0; i < 4; i++)
      qb[((size_t)bb * NP + prow0 + i) * NCQ + c] = f2bf(acc[nt][i] + bias);
  }
  #pragma unroll
  for (int nt = 18; nt < 20; nt++){
    int c = (nt - 18) * 16 + col;
    float bias = bk[c];
    #pragma unroll
    for (int i = 0; i < 4; i++)
      kb[((size_t)bb * NP + prow0 + i) * NCQ + c] = f2bf(acc[nt][i] + bias);
  }
}

// ---------- 5. eH scores (diag masked): att[b][ih*96+w][j], j<96 ----------
__global__ __launch_bounds__(256)
void k_eH(const unsigned short* __restrict__ qb, const unsigned short* __restrict__ kb,
          unsigned short* __restrict__ att){
  int w = blockIdx.x, bb = blockIdx.y;      // (96, NB)
  __shared__ float ql[96 * 33], kl[96 * 33];
  for (int idx = threadIdx.x; idx < 96 * 8; idx += 256){
    int r = idx >> 3, g = (idx & 7) * 4;
    size_t src = ((size_t)bb * NP + (r * 96 + w)) * NCQ + g;
    uint2 qu = *(const uint2*)(qb + src);
    uint2 ku = *(const uint2*)(kb + src);
    ql[r * 33 + g + 0] = bflo(qu.x); ql[r * 33 + g + 1] = bfhi(qu.x);
    ql[r * 33 + g + 2] = bflo(qu.y); ql[r * 33 + g + 3] = bfhi(qu.y);
    kl[r * 33 + g + 0] = bflo(ku.x); kl[r * 33 + g + 1] = bfhi(ku.x);
    kl[r * 33 + g + 2] = bflo(ku.y); kl[r * 33 + g + 3] = bfhi(ku.y);
  }
  __syncthreads();
  int tx = threadIdx.x & 15, ty = threadIdx.x >> 4;
  int i0 = ty * 6, j0 = tx * 6;
  float acc[6][6] = {};
  for (int c = 0; c < 32; c++){
    float a[6], b[6];
    #pragma unroll
    for (int i = 0; i < 6; i++) a[i] = ql[(i0 + i) * 33 + c];
    #pragma unroll
    for (int j = 0; j < 6; j++) b[j] = kl[(j0 + j) * 33 + c];
    #pragma unroll
    for (int i = 0; i < 6; i++)
      #pragma unroll
      for (int j = 0; j < 6; j++) acc[i][j] = fmaf(a[i], b[j], acc[i][j]);
  }
  #pragma unroll
  for (int i = 0; i < 6; i++){
    int ih = i0 + i;
    size_t rowbase = ((size_t)bb * NP + (ih * 96 + w)) * NL;
    #pragma unroll
    for (int j = 0; j < 6; j++){
      int jh = j0 + j;
      float v = (jh == ih) ? -INFINITY : acc[i][j];
      att[rowbase + jh] = f2bf(v);
    }
  }
}

// ---------- 6. eW scores: att[b][h*96+i][96+j] ----------
__global__ __launch_bounds__(256)
void k_eW(const unsigned short* __restrict__ qb, const unsigned short* __restrict__ kb,
          unsigned short* __restrict__ att){
  int h = blockIdx.x, bb = blockIdx.y;      // (96, NB)
  __shared__ float ql[96 * 33], kl[96 * 33];
  for (int idx = threadIdx.x; idx < 96 * 8; idx += 256){
    int r = idx >> 3, g = (idx & 7) * 4;
    size_t src = ((size_t)bb * NP + (h * 96 + r)) * NCQ + g;
    uint2 qu = *(const uint2*)(qb + src);
    uint2 ku = *(const uint2*)(kb + src);
    ql[r * 33 + g + 0] = bflo(qu.x); ql[r * 33 + g + 1] = bfhi(qu.x);
    ql[r * 33 + g + 2] = bflo(qu.y); ql[r * 33 + g + 3] = bfhi(qu.y);
    kl[r * 33 + g + 0] = bflo(ku.x); kl[r * 33 + g + 1] = bfhi(ku.x);
    kl[r * 33 + g + 2] = bflo(ku.y); kl[r * 33 + g + 3] = bfhi(ku.y);
  }
  __syncthreads();
  int tx = threadIdx.x & 15, ty = threadIdx.x >> 4;
  int i0 = ty * 6, j0 = tx * 6;
  float acc[6][6] = {};
  for (int c = 0; c < 32; c++){
    float a[6], b[6];
    #pragma unroll
    for (int i = 0; i < 6; i++) a[i] = ql[(i0 + i) * 33 + c];
    #pragma unroll
    for (int j = 0; j < 6; j++) b[j] = kl[(j0 + j) * 33 + c];
    #pragma unroll
    for (int i = 0; i < 6; i++)
      #pragma unroll
      for (int j = 0; j < 6; j++) acc[i][j] = fmaf(a[i], b[j], acc[i][j]);
  }
  #pragma unroll
  for (int i = 0; i < 6; i++){
    size_t rowbase = ((size_t)bb * NP + (h * 96 + i0 + i)) * NL + 96;
    #pragma unroll
    for (int j = 0; j < 6; j++) att[rowbase + j0 + j] = f2bf(acc[i][j]);
  }
}

// ---------- 7. softmax over 192 per query ----------
__global__ __launch_bounds__(256)
void k_attSoftmax(unsigned short* __restrict__ att){
  int q = blockIdx.x * 4 + (threadIdx.x >> 6);
  int lane = threadIdx.x & 63;
  unsigned short* row = att + (size_t)q * NL;
  float e0 = bf2f(row[lane]);
  float e1 = bf2f(row[64 + lane]);
  float e2 = bf2f(row[128 + lane]);
  float m = fmaxf(e0, fmaxf(e1, e2));
  m = warpReduceMax(m);
  float x0 = expf(e0 - m), x1 = expf(e1 - m), x2 = expf(e2 - m);
  float s = warpReduceSum(x0 + x1 + x2);
  float rs = 1.f / s;
  row[lane]       = f2bf(x0 * rs);
  row[64 + lane]  = f2bf(x1 * rs);
  row[128 + lane] = f2bf(x2 * rs);
}

// ---------- 8. outH: OH[b][i*96+w][c] = sum_j attH[(i,w),j] * V[b][j*96+w][c] ----------
__global__ __launch_bounds__(128)
void k_outH(const unsigned short* __restrict__ V, const unsigned short* __restrict__ att,
            unsigned short* __restrict__ OH){
  int iq = blockIdx.x, w = blockIdx.y, bb = blockIdx.z;  // (4, 96, NB)
  __shared__ float al[96 * 28];
  for (int idx = threadIdx.x; idx < 24 * 96; idx += 128){
    int ii = idx / 96, j = idx % 96;
    al[j * 28 + ii] = bf2f(att[((size_t)bb * NP + ((iq * 24 + ii) * 96 + w)) * NL + j]);
  }
  __syncthreads();
  int c0 = threadIdx.x * 2;
  float acc[24][2] = {};
  for (int j = 0; j < 96; j++){
    unsigned uv = *(const unsigned*)(V + ((size_t)bb * NP + j * 96 + w) * NC + c0);
    float v0 = bflo(uv), v1 = bfhi(uv);
    #pragma unroll
    for (int ic = 0; ic < 6; ic++){
      F4 a; a.v = *(const float4*)(al + j * 28 + ic * 4);
      #pragma unroll
      for (int r = 0; r < 4; r++){
        acc[ic * 4 + r][0] = fmaf(a.a[r], v0, acc[ic * 4 + r][0]);
        acc[ic * 4 + r][1] = fmaf(a.a[r], v1, acc[ic * 4 + r][1]);
      }
    }
  }
  #pragma unroll
  for (int ii = 0; ii < 24; ii++){
    size_t base = ((size_t)bb * NP + (iq * 24 + ii) * 96 + w) * NC + c0;
    unsigned outp = (unsigned)f2bf(acc[ii][0]) | ((unsigned)f2bf(acc[ii][1]) << 16);
    *(unsigned*)(OH + base) = outp;
  }
}

// ---------- 9. outW + total O; T pass stores Ot; S pass fuses loss ----------
__global__ __launch_bounds__(128)
void k_outW(const unsigned short* __restrict__ V, const unsigned short* __restrict__ att,
            const unsigned short* __restrict__ OH, unsigned short* __restrict__ Ot,
            const float* __restrict__ predsS, const float* __restrict__ predsT,
            const float* __restrict__ mean, const float* __restrict__ inv,
            const float* __restrict__ gamma, int b0, int spass,
            float* __restrict__ out){
  int iq = blockIdx.x, h = blockIdx.y, bb = blockIdx.z;  // (4, 96, NB)
  __shared__ float al[96 * 28];
  for (int idx = threadIdx.x; idx < 24 * 96; idx += 128){
    int ii = idx / 96, j = idx % 96;
    al[j * 28 + ii] = bf2f(att[((size_t)bb * NP + (h * 96 + (iq * 24 + ii))) * NL + 96 + j]);
  }
  __syncthreads();
  int c0 = threadIdx.x * 2;
  float acc[24][2] = {};
  for (int j = 0; j < 96; j++){
    unsigned uv = *(const unsigned*)(V + ((size_t)bb * NP + h * 96 + j) * NC + c0);
    float v0 = bflo(uv), v1 = bfhi(uv);
    #pragma unroll
    for (int ic = 0; ic < 6; ic++){
      F4 a; a.v = *(const float4*)(al + j * 28 + ic * 4);
      #pragma unroll
      for (int r = 0; r < 4; r++){
        acc[ic * 4 + r][0] = fmaf(a.a[r], v0, acc[ic * 4 + r][0]);
        acc[ic * 4 + r][1] = fmaf(a.a[r], v1, acc[ic * 4 + r][1]);
      }
    }
  }
  if (!spass){
    #pragma unroll
    for (int ii = 0; ii < 24; ii++){
      int i = iq * 24 + ii;
      size_t base = ((size_t)bb * NP + h * 96 + i) * NC + c0;
      unsigned uoh = *(const unsigned*)(OH + base);
      float t0 = acc[ii][0] + bflo(uoh);
      float t1 = acc[ii][1] + bfhi(uoh);
      unsigned outp = (unsigned)f2bf(t0) | ((unsigned)f2bf(t1) << 16);
      *(unsigned*)(Ot + base) = outp;
    }
  } else {
    int bg = b0 + bb;
    float g = gamma[0];
    int c1 = c0 + 1;
    float mS0 = mean[c0],      iS0 = inv[c0];
    float mS1 = mean[c1],      iS1 = inv[c1];
    float mT0 = mean[NC + c0], iT0 = inv[NC + c0];
    float mT1 = mean[NC + c1], iT1 = inv[NC + c1];
    const float* tp0 = predsT + ((size_t)bg * NC + c0) * NP + h * 96;
    const float* tp1 = predsT + ((size_t)bg * NC + c1) * NP + h * 96;
    const float* sp0 = predsS + ((size_t)bg * NC + c0) * NP + h * 96;
    const float* sp1 = predsS + ((size_t)bg * NC + c1) * NP + h * 96;
    float ss = 0.f;
    #pragma unroll
    for (int ic = 0; ic < 6; ic++){
      int ib = iq * 24 + ic * 4;
      F4 tA, tB, sA, sB;
      tA.v = *(const float4*)(tp0 + ib);
      tB.v = *(const float4*)(tp1 + ib);
      sA.v = *(const float4*)(sp0 + ib);
      sB.v = *(const float4*)(sp1 + ib);
      #pragma unroll
      for (int r = 0; r < 4; r++){
        int ii = ic * 4 + r;
        int i = ib + r;
        size_t base = ((size_t)bb * NP + h * 96 + i) * NC + c0;
        unsigned uoh = *(const unsigned*)(OH + base);
        unsigned uot = *(const unsigned*)(Ot + base);
        float os0 = acc[ii][0] + bflo(uoh);
        float os1 = acc[ii][1] + bfhi(uoh);
        float dn0 = (tA.a[r] - mT0) * iT0 - (sA.a[r] - mS0) * iS0;
        float dn1 = (tB.a[r] - mT1) * iT1 - (sB.a[r] - mS1) * iS1;
        float d0 = g * (bflo(uot) - os0) + dn0;
        float d1 = g * (bfhi(uot) - os1) + dn1;
        ss += d0 * d0 + d1 * d1;
      }
    }
    ss = blockReduceSum(ss);
    if (threadIdx.x == 0) atomicAdd(out, ss * (1e-5f / 8.0f));
  }
}

// ---------- host ----------
extern "C" void kernel_launch(void* const* d_in, const int* in_sizes, int n_in,
                              void* d_out, int out_size, void* d_ws, size_t ws_size,
                              hipStream_t stream){
  (void)in_sizes; (void)n_in; (void)out_size;
  const float* S    = (const float*)d_in[0];
  const float* T    = (const float*)d_in[1];
  const float* wcls = (const float*)d_in[2];
  const float* wq   = (const float*)d_in[3];
  const float* bq   = (const float*)d_in[4];
  const float* wk   = (const float*)d_in[5];
  const float* bk   = (const float*)d_in[6];
  const float* wv   = (const float*)d_in[7];
  const float* bv   = (const float*)d_in[8];
  const float* gamma= (const float*)d_in[9];
  float* out = (float*)d_out;

  char* base = (char*)d_ws;
  size_t off = 0;
  auto alloc = [&](size_t b){ size_t o = off; off += (b + 255) & ~(size_t)255; return o; };
  size_t o_ssum = alloc(2 * NC * 4);
  size_t o_ssq  = alloc(2 * NC * 4);
  size_t o_mean = alloc(2 * NC * 4);
  size_t o_inv  = alloc(2 * NC * 4);
  size_t o_ca   = alloc((size_t)2 * NBAT * NKC * NC * 4);
  size_t o_smca = alloc((size_t)2 * NBAT * NKC * NP * 4);
  size_t fixed = off;
  size_t per_b = (size_t)NP * NC * 2 * 4       // XN + V + OH + Ot (bf16)
               + (size_t)NP * NCQ * 2 * 2      // q + k (bf16)
               + (size_t)NP * NL * 2;          // att (bf16)
  int NB = 8;
  while (NB > 1 && fixed + (size_t)NB * per_b + 8192 > ws_size) NB >>= 1;

  size_t o_xn  = alloc((size_t)NB * NP * NC * 2);
  size_t o_v   = alloc((size_t)NB * NP * NC * 2);
  size_t o_q   = alloc((size_t)NB * NP * NCQ * 2);
  size_t o_k   = alloc((size_t)NB * NP * NCQ * 2);
  size_t o_att = alloc((size_t)NB * NP * NL * 2);
  size_t o_oh  = alloc((size_t)NB * NP * NC * 2);
  size_t o_ot  = alloc((size_t)NB * NP * NC * 2);

  float* ssum = (float*)(base + o_ssum);
  float* ssq  = (float*)(base + o_ssq);
  float* mean = (float*)(base + o_mean);
  float* inv  = (float*)(base + o_inv);
  float* ca   = (float*)(base + o_ca);
  float* smca = (float*)(base + o_smca);
  unsigned short* XN  = (unsigned short*)(base + o_xn);
  unsigned short* V   = (unsigned short*)(base + o_v);
  unsigned short* qbp = (unsigned short*)(base + o_q);
  unsigned short* kbp = (unsigned short*)(base + o_k);
  unsigned short* att = (unsigned short*)(base + o_att);
  unsigned short* OH  = (unsigned short*)(base + o_oh);
  unsigned short* Ot  = (unsigned short*)(base + o_ot);

  hipMemsetAsync(d_out, 0, 4, stream);
  hipMemsetAsync(base + o_ssum, 0, 4096, stream);
  hipMemsetAsync(base + o_ca, 0, (size_t)2 * NBAT * NKC * NC * 4, stream);

  k_stats<<<dim3(2 * NC * NBAT), 256, 0, stream>>>(S, T, ssum, ssq);
  k_finalize<<<1, 512, 0, stream>>>(ssum, ssq, mean, inv);

  // causal attention (both tensors, full batch)
  k_caM<<<dim3(36, NBAT, 2), 256, 0, stream>>>(S, T, wcls, mean, inv, smca);
  k_caSoftmax<<<dim3(2 * NBAT * NKC), 256, 0, stream>>>(smca);
  k_caOut<<<dim3(48, NBAT, 2), 256, 0, stream>>>(S, T, smca, mean, inv, ca);
  k_caLoss<<<dim3(48), 256, 0, stream>>>(ca, out);

  // ccnet: per batch-chunk, tensor T then S (loss fused into S outW)
  for (int b0 = 0; b0 < NBAT; b0 += NB){
    for (int pass = 0; pass < 2; pass++){
      int t = (pass == 0) ? 1 : 0;
      const float* x = t ? T : S;
      k_xn<<<dim3(144, 4, NB), 256, 0, stream>>>(x, b0, mean, inv, t, XN);
      k_v<<<dim3(144, NB), 256, 0, stream>>>(XN, wv, bv, wq, bq, wk, bk, V, qbp, kbp);
      k_eH<<<dim3(96, NB), 256, 0, stream>>>(qbp, kbp, att);
      k_eW<<<dim3(96, NB), 256, 0, stream>>>(qbp, kbp, att);
      k_attSoftmax<<<dim3(NB * 2304), 256, 0, stream>>>(att);
      k_outH<<<dim3(4, 96, NB), 128, 0, stream>>>(V, att, OH);
      k_outW<<<dim3(4, 96, NB), 128, 0, stream>>>(V, att, OH, Ot, S, T, mean, inv,
                                                  gamma, b0, pass, out);
    }
  }
}

// Round 3
// 750.104 us; speedup vs baseline: 2.0523x; 1.2284x over previous
//
#include <hip/hip_runtime.h>
#include <math.h>

#define NBAT 8
#define NC   256
#define NH   96
#define NW   96
#define NP   9216
#define NCQ  32
#define NKC  6
#define NL   192
#define NV   320          // 256 v-channels + 32 q + 32 k
#define NTOT 73728        // NBAT*NP

typedef __attribute__((ext_vector_type(4))) float  floatx4;
typedef __attribute__((ext_vector_type(8))) short  short8;

// ---------- bf16 helpers (storage only; math fp32) ----------
__device__ __forceinline__ float bf2f(unsigned short h){
  return __uint_as_float(((unsigned)h) << 16);
}
__device__ __forceinline__ float bflo(unsigned u){ return __uint_as_float(u << 16); }
__device__ __forceinline__ float bfhi(unsigned u){ return __uint_as_float(u & 0xFFFF0000u); }
__device__ __forceinline__ unsigned short f2bf(float f){
  unsigned u = __float_as_uint(f);
  u += 0x7FFFu + ((u >> 16) & 1u);
  return (unsigned short)(u >> 16);
}

union F4 { float4 v; float a[4]; };

// ---------- reductions ----------
__device__ __forceinline__ float warpReduceSum(float v){
  #pragma unroll
  for (int m = 32; m; m >>= 1) v += __shfl_xor(v, m);
  return v;
}
__device__ __forceinline__ float warpReduceMax(float v){
  #pragma unroll
  for (int m = 32; m; m >>= 1) v = fmaxf(v, __shfl_xor(v, m));
  return v;
}
__device__ float blockReduceSum(float v){
  __shared__ float lds[8];
  v = warpReduceSum(v);
  int wid = threadIdx.x >> 6, lane = threadIdx.x & 63;
  int nw = blockDim.x >> 6;
  if (lane == 0) lds[wid] = v;
  __syncthreads();
  if (wid == 0){
    v = (lane < nw) ? lds[lane] : 0.f;
    #pragma unroll
    for (int m = 4; m; m >>= 1) v += __shfl_xor(v, m);
  }
  __syncthreads();
  return v;  // valid on thread 0
}
__device__ float blockReduceMax(float v){
  __shared__ float lds[8];
  v = warpReduceMax(v);
  int wid = threadIdx.x >> 6, lane = threadIdx.x & 63;
  int nw = blockDim.x >> 6;
  if (lane == 0) lds[wid] = v;
  __syncthreads();
  if (wid == 0){
    v = (lane < nw) ? lds[lane] : -INFINITY;
    #pragma unroll
    for (int m = 4; m; m >>= 1) v = fmaxf(v, __shfl_xor(v, m));
  }
  __syncthreads();
  return v;
}

// ---------- 1. per-channel stats ----------
__global__ __launch_bounds__(256)
void k_stats(const float* __restrict__ S, const float* __restrict__ T,
             float* __restrict__ s_sum, float* __restrict__ s_sq){
  int blk = blockIdx.x;                 // 2*C*B = 4096
  int t = blk / (NC * NBAT);
  int rem = blk % (NC * NBAT);
  int c = rem / NBAT;
  int n = rem % NBAT;
  const float* x = (t ? T : S) + ((size_t)n * NC + c) * NP;
  float s = 0.f, q = 0.f;
  for (int p = threadIdx.x; p < NP; p += 256){ float v = x[p]; s += v; q += v * v; }
  s = blockReduceSum(s);
  q = blockReduceSum(q);
  if (threadIdx.x == 0){
    atomicAdd(&s_sum[t * NC + c], s);
    atomicAdd(&s_sq[t * NC + c], q);
  }
}

__global__ __launch_bounds__(512)
void k_finalize(const float* __restrict__ s_sum, const float* __restrict__ s_sq,
                float* __restrict__ mean, float* __restrict__ inv){
  int i = threadIdx.x;
  if (i < 2 * NC){
    float s = s_sum[i], q = s_sq[i];
    float m = s / (float)NTOT;
    float var = (q - s * m) / (float)(NTOT - 1);
    var = fmaxf(var, 0.f);
    mean[i] = m;
    inv[i] = 1.f / (sqrtf(var) + 1e-6f);
  }
}

// ---------- 2. causal attention ----------
__global__ __launch_bounds__(256)
void k_caM(const float* __restrict__ S, const float* __restrict__ T,
           const float* __restrict__ wcls,
           const float* __restrict__ mean, const float* __restrict__ inv,
           float* __restrict__ smca){
  int pt = blockIdx.x, n = blockIdx.y, t = blockIdx.z;   // (36, 8, 2)
  __shared__ float wsc[NKC * NC];
  __shared__ float shift[NKC];
  for (int idx = threadIdx.x; idx < NKC * NC; idx += 256){
    int c = idx & 255;
    wsc[idx] = wcls[idx] * inv[t * NC + c];
  }
  __syncthreads();
  if (threadIdx.x < NKC){
    float sh = 0.f;
    for (int c = 0; c < NC; c++) sh += wsc[threadIdx.x * NC + c] * mean[t * NC + c];
    shift[threadIdx.x] = sh;
  }
  __syncthreads();
  int p = pt * 256 + threadIdx.x;
  const float* x = (t ? T : S) + (size_t)n * NC * NP + p;
  float acc[NKC];
  #pragma unroll
  for (int k = 0; k < NKC; k++) acc[k] = 0.f;
  for (int c = 0; c < NC; c++){
    float xv = x[(size_t)c * NP];
    #pragma unroll
    for (int k = 0; k < NKC; k++) acc[k] += wsc[k * NC + c] * xv;
  }
  size_t base = ((size_t)(t * NBAT + n) * NKC) * NP + p;
  #pragma unroll
  for (int k = 0; k < NKC; k++) smca[base + (size_t)k * NP] = acc[k] - shift[k];
}

__global__ __launch_bounds__(256)
void k_caSoftmax(float* __restrict__ smca){
  int r = blockIdx.x;                      // 96 rows
  float* row = smca + (size_t)r * NP;
  float m = -INFINITY;
  for (int p = threadIdx.x; p < NP; p += 256) m = fmaxf(m, row[p]);
  m = blockReduceMax(m);
  __shared__ float bm, bs;
  if (threadIdx.x == 0) bm = m;
  __syncthreads();
  m = bm;
  float s = 0.f;
  for (int p = threadIdx.x; p < NP; p += 256) s += expf(row[p] - m);
  s = blockReduceSum(s);
  if (threadIdx.x == 0) bs = 1.f / s;
  __syncthreads();
  float rs = bs;
  for (int p = threadIdx.x; p < NP; p += 256) row[p] = expf(row[p] - m) * rs;
}

// split-K caOut: grid.x = ct(8) + 8*ks(6)
__global__ __launch_bounds__(256)
void k_caOut(const float* __restrict__ S, const float* __restrict__ T,
             const float* __restrict__ smca,
             const float* __restrict__ mean, const float* __restrict__ inv,
             float* __restrict__ ca){
  int ct = blockIdx.x & 7, ks = blockIdx.x >> 3;
  int n = blockIdx.y, t = blockIdx.z;   // (48, 8, 2)
  int c0 = ct * 32;
  __shared__ float xt[32 * 264];
  __shared__ float smt[NKC * 256];
  int cl = threadIdx.x >> 3, pl = threadIdx.x & 7;
  float acc[NKC];
  #pragma unroll
  for (int k = 0; k < NKC; k++) acc[k] = 0.f;
  const float* xbase = (t ? T : S) + (size_t)n * NC * NP;
  const float* smbase = smca + (size_t)(t * NBAT + n) * NKC * NP;
  for (int pt = ks * 6; pt < ks * 6 + 6; pt++){
    int p0 = pt * 256;
    for (int idx = threadIdx.x; idx < 32 * 256; idx += 256){
      int r = idx >> 8, p = idx & 255;
      float v = xbase[(size_t)(c0 + r) * NP + p0 + p];
      xt[r * 264 + p] = (v - mean[t * NC + c0 + r]) * inv[t * NC + c0 + r];
    }
    for (int idx = threadIdx.x; idx < NKC * 256; idx += 256){
      int k = idx >> 8, p = idx & 255;
      smt[idx] = smbase[(size_t)k * NP + p0 + p];
    }
    __syncthreads();
    for (int j = 0; j < 32; j++){
      float xv = xt[cl * 264 + pl + 8 * j];
      #pragma unroll
      for (int k = 0; k < NKC; k++) acc[k] += smt[k * 256 + pl + 8 * j] * xv;
    }
    __syncthreads();
  }
  #pragma unroll
  for (int k = 0; k < NKC; k++){
    float v = acc[k];
    v += __shfl_xor(v, 1); v += __shfl_xor(v, 2); v += __shfl_xor(v, 4);
    if (pl == 0) atomicAdd(&ca[((size_t)(t * NBAT + n) * NKC + k) * NC + c0 + cl], v);
  }
}

__global__ __launch_bounds__(256)
void k_caLoss(const float* __restrict__ ca, float* __restrict__ out){
  int i = blockIdx.x * 256 + threadIdx.x;   // 12288 total
  float d = 0.f;
  if (i < NBAT * NKC * NC) d = ca[(size_t)NBAT * NKC * NC + i] - ca[i];
  float ss = blockReduceSum(d * d);
  if (threadIdx.x == 0) atomicAdd(out, ss * (0.0005f / 8.0f));
}

// ---------- 3. stage normalized x as bf16 XN[b][p][c] (transpose) ----------
__global__ __launch_bounds__(256)
void k_xn(const float* __restrict__ x0, int b0,
          const float* __restrict__ mean, const float* __restrict__ inv, int t,
          unsigned short* __restrict__ XN){
  int pt = blockIdx.x, ct = blockIdx.y, bb = blockIdx.z;  // (144, 4, NB)
  int bg = b0 + bb;
  int p0 = pt * 64, c0 = ct * 64;
  __shared__ float tile[64 * 65];
  const float* x = x0 + ((size_t)bg * NC + c0) * NP + p0;
  #pragma unroll
  for (int i = 0; i < 4; i++){
    int idx = threadIdx.x + i * 256;       // 64 c-rows x 16 float4 groups
    int r = idx >> 4, g = (idx & 15) * 4;
    F4 f; f.v = *(const float4*)(x + (size_t)r * NP + g);
    float m = mean[t * NC + c0 + r], iv = inv[t * NC + c0 + r];
    #pragma unroll
    for (int j = 0; j < 4; j++) tile[(g + j) * 65 + r] = (f.a[j] - m) * iv;
  }
  __syncthreads();
  #pragma unroll
  for (int i = 0; i < 4; i++){
    int idx = threadIdx.x + i * 256;       // 64 p-rows x 16 groups of 4c
    int p = idx >> 4, g = (idx & 15) * 4;
    unsigned lo = (unsigned)f2bf(tile[p * 65 + g + 0]) | ((unsigned)f2bf(tile[p * 65 + g + 1]) << 16);
    unsigned hi = (unsigned)f2bf(tile[p * 65 + g + 2]) | ((unsigned)f2bf(tile[p * 65 + g + 3]) << 16);
    uint2 u; u.x = lo; u.y = hi;
    *(uint2*)(XN + ((size_t)bb * NP + p0 + p) * NC + c0 + g) = u;
  }
}

// ---------- 4. MFMA GEMM: XN[p x 256] @ W^T -> VT1[b][c][p] + q,k [p][cq] ----------
__global__ __launch_bounds__(256)
void k_v(const unsigned short* __restrict__ XN,
         const float* __restrict__ wv, const float* __restrict__ bv,
         const float* __restrict__ wq, const float* __restrict__ bq,
         const float* __restrict__ wk, const float* __restrict__ bk,
         unsigned short* __restrict__ VT1,
         unsigned short* __restrict__ qb, unsigned short* __restrict__ kb){
  int pt = blockIdx.x, bb = blockIdx.y;   // (144, NB)
  int p0 = pt * 64;
  __shared__ unsigned short Wl[NV * 40];
  int lane = threadIdx.x & 63;
  int wid = threadIdx.x >> 6;
  int col = lane & 15, quad = lane >> 4;
  const unsigned short* xnb = XN + (size_t)bb * NP * NC;
  floatx4 acc[20];
  #pragma unroll
  for (int nt = 0; nt < 20; nt++) acc[nt] = (floatx4){0.f, 0.f, 0.f, 0.f};

  for (int ks = 0; ks < 8; ks++){
    int k0 = ks * 32;
    for (int n = threadIdx.x; n < NV; n += 256){
      const float* src = (n < 256) ? (wv + (size_t)n * NC + k0)
                       : (n < 288) ? (wq + (size_t)(n - 256) * NC + k0)
                                   : (wk + (size_t)(n - 288) * NC + k0);
      unsigned short* dst = Wl + n * 40;
      #pragma unroll
      for (int i = 0; i < 8; i++){
        F4 f; f.v = *(const float4*)(src + i * 4);
        dst[i * 4 + 0] = f2bf(f.a[0]);
        dst[i * 4 + 1] = f2bf(f.a[1]);
        dst[i * 4 + 2] = f2bf(f.a[2]);
        dst[i * 4 + 3] = f2bf(f.a[3]);
      }
    }
    __syncthreads();
    short8 a = *(const short8*)(xnb + (size_t)(p0 + wid * 16 + col) * NC + k0 + quad * 8);
    #pragma unroll
    for (int nt = 0; nt < 20; nt++){
      short8 b = *(const short8*)(Wl + (nt * 16 + col) * 40 + quad * 8);
      acc[nt] = __builtin_amdgcn_mfma_f32_16x16x32_bf16(a, b, acc[nt], 0, 0, 0);
    }
    __syncthreads();
  }

  int prow0 = p0 + wid * 16 + quad * 4;
  #pragma unroll
  for (int nt = 0; nt < 16; nt++){
    int c = nt * 16 + col;
    float bias = bv[c];
    uint2 u;
    u.x = (unsigned)f2bf(acc[nt][0] + bias) | ((unsigned)f2bf(acc[nt][1] + bias) << 16);
    u.y = (unsigned)f2bf(acc[nt][2] + bias) | ((unsigned)f2bf(acc[nt][3] + bias) << 16);
    *(uint2*)(VT1 + ((size_t)bb * NC + c) * NP + prow0) = u;
  }
  #pragma unroll
  for (int nt = 16; nt < 18; nt++){
    int c = (nt - 16) * 16 + col;
    float bias = bq[c];
    #pragma unroll
    for (int i = 0; i < 4; i++)
      qb[((size_t)bb * NP + prow0 + i) * NCQ + c] = f2bf(acc[nt][i] + bias);
  }
  #pragma unroll
  for (int nt = 18; nt < 20; nt++){
    int c = (nt - 18) * 16 + col;
    float bias = bk[c];
    #pragma unroll
    for (int i = 0; i < 4; i++)
      kb[((size_t)bb * NP + prow0 + i) * NCQ + c] = f2bf(acc[nt][i] + bias);
  }
}

// ---------- 4b. spatial transpose: VT2[b][c][w*96+h] = VT1[b][c][h*96+w] ----------
__global__ __launch_bounds__(256)
void k_vt(const unsigned short* __restrict__ VT1, unsigned short* __restrict__ VT2){
  int c = blockIdx.x, bb = blockIdx.y;    // (256, NB)
  __shared__ unsigned short tile[96 * 104];  // [w][h], stride 104 (16B-aligned rows)
  size_t base = ((size_t)bb * NC + c) * NP;
  for (int idx = threadIdx.x; idx < 1152; idx += 256){
    int h = idx / 12, g = idx % 12;
    short8 v = *(const short8*)(VT1 + base + h * 96 + g * 8);
    #pragma unroll
    for (int kk = 0; kk < 8; kk++) tile[(g * 8 + kk) * 104 + h] = ((unsigned short*)&v)[kk];
  }
  __syncthreads();
  for (int idx = threadIdx.x; idx < 1152; idx += 256){
    int w = idx / 12, g = idx % 12;
    short8 v = *(const short8*)(tile + w * 104 + g * 8);
    *(short8*)(VT2 + base + w * 96 + g * 8) = v;
  }
}

// ---------- 5. eH scores (MFMA, diag masked): att[b][i*96+w][j], j<96 ----------
__global__ __launch_bounds__(256)
void k_eH(const unsigned short* __restrict__ qb, const unsigned short* __restrict__ kb,
          unsigned short* __restrict__ att){
  int w = blockIdx.x, bb = blockIdx.y;      // (96, NB)
  int lane = threadIdx.x & 63, wid = threadIdx.x >> 6;
  int col = lane & 15, quad = lane >> 4;
  int mi0 = (wid & 1) * 3, ni0 = (wid >> 1) * 3;
  short8 a[3], b[3];
  #pragma unroll
  for (int m = 0; m < 3; m++)
    a[m] = *(const short8*)(qb + ((size_t)bb * NP + ((mi0 + m) * 16 + col) * 96 + w) * NCQ + quad * 8);
  #pragma unroll
  for (int n = 0; n < 3; n++)
    b[n] = *(const short8*)(kb + ((size_t)bb * NP + ((ni0 + n) * 16 + col) * 96 + w) * NCQ + quad * 8);
  floatx4 acc[3][3];
  #pragma unroll
  for (int m = 0; m < 3; m++)
    #pragma unroll
    for (int n = 0; n < 3; n++){
      acc[m][n] = (floatx4){0.f, 0.f, 0.f, 0.f};
      acc[m][n] = __builtin_amdgcn_mfma_f32_16x16x32_bf16(a[m], b[n], acc[m][n], 0, 0, 0);
    }
  #pragma unroll
  for (int m = 0; m < 3; m++)
    #pragma unroll
    for (int n = 0; n < 3; n++){
      int j = (ni0 + n) * 16 + col;
      #pragma unroll
      for (int r = 0; r < 4; r++){
        int i = (mi0 + m) * 16 + quad * 4 + r;
        float v = (j == i) ? -INFINITY : acc[m][n][r];
        att[((size_t)bb * NP + i * 96 + w) * NL + j] = f2bf(v);
      }
    }
}

// ---------- 6. eW scores (MFMA): att[b][h*96+i][96+j] ----------
__global__ __launch_bounds__(256)
void k_eW(const unsigned short* __restrict__ qb, const unsigned short* __restrict__ kb,
          unsigned short* __restrict__ att){
  int h = blockIdx.x, bb = blockIdx.y;      // (96, NB)
  int lane = threadIdx.x & 63, wid = threadIdx.x >> 6;
  int col = lane & 15, quad = lane >> 4;
  int mi0 = (wid & 1) * 3, ni0 = (wid >> 1) * 3;
  short8 a[3], b[3];
  #pragma unroll
  for (int m = 0; m < 3; m++)
    a[m] = *(const short8*)(qb + ((size_t)bb * NP + h * 96 + (mi0 + m) * 16 + col) * NCQ + quad * 8);
  #pragma unroll
  for (int n = 0; n < 3; n++)
    b[n] = *(const short8*)(kb + ((size_t)bb * NP + h * 96 + (ni0 + n) * 16 + col) * NCQ + quad * 8);
  floatx4 acc[3][3];
  #pragma unroll
  for (int m = 0; m < 3; m++)
    #pragma unroll
    for (int n = 0; n < 3; n++){
      acc[m][n] = (floatx4){0.f, 0.f, 0.f, 0.f};
      acc[m][n] = __builtin_amdgcn_mfma_f32_16x16x32_bf16(a[m], b[n], acc[m][n], 0, 0, 0);
    }
  #pragma unroll
  for (int m = 0; m < 3; m++)
    #pragma unroll
    for (int n = 0; n < 3; n++){
      int j = (ni0 + n) * 16 + col;
      #pragma unroll
      for (int r = 0; r < 4; r++){
        int i = (mi0 + m) * 16 + quad * 4 + r;
        att[((size_t)bb * NP + h * 96 + i) * NL + 96 + j] = f2bf(acc[m][n][r]);
      }
    }
}

// ---------- 7. softmax over 192 per query ----------
__global__ __launch_bounds__(256)
void k_attSoftmax(unsigned short* __restrict__ att){
  int q = blockIdx.x * 4 + (threadIdx.x >> 6);
  int lane = threadIdx.x & 63;
  unsigned short* row = att + (size_t)q * NL;
  float e0 = bf2f(row[lane]);
  float e1 = bf2f(row[64 + lane]);
  float e2 = bf2f(row[128 + lane]);
  float m = fmaxf(e0, fmaxf(e1, e2));
  m = warpReduceMax(m);
  float x0 = expf(e0 - m), x1 = expf(e1 - m), x2 = expf(e2 - m);
  float s = warpReduceSum(x0 + x1 + x2);
  float rs = 1.f / s;
  row[lane]       = f2bf(x0 * rs);
  row[64 + lane]  = f2bf(x1 * rs);
  row[128 + lane] = f2bf(x2 * rs);
}

// ---------- 8. outH (MFMA): OH[i*96+w][c] = sum_j attH[(i,w),j] * VT2[c][w*96+j] ----------
__global__ __launch_bounds__(256)
void k_outH(const unsigned short* __restrict__ VT2, const unsigned short* __restrict__ att,
            unsigned short* __restrict__ OH){
  int w = blockIdx.x, bb = blockIdx.y;    // (96, NB)
  int lane = threadIdx.x & 63, wid = threadIdx.x >> 6;
  int col = lane & 15, quad = lane >> 4;
  floatx4 acc[6][4];
  #pragma unroll
  for (int m = 0; m < 6; m++)
    #pragma unroll
    for (int n = 0; n < 4; n++) acc[m][n] = (floatx4){0.f, 0.f, 0.f, 0.f};
  #pragma unroll
  for (int ks = 0; ks < 3; ks++){
    int k0 = ks * 32 + quad * 8;
    short8 a[6], b[4];
    #pragma unroll
    for (int m = 0; m < 6; m++)
      a[m] = *(const short8*)(att + ((size_t)bb * NP + (m * 16 + col) * 96 + w) * NL + k0);
    #pragma unroll
    for (int n = 0; n < 4; n++){
      int c = wid * 64 + n * 16 + col;
      b[n] = *(const short8*)(VT2 + ((size_t)bb * NC + c) * NP + w * 96 + k0);
    }
    #pragma unroll
    for (int m = 0; m < 6; m++)
      #pragma unroll
      for (int n = 0; n < 4; n++)
        acc[m][n] = __builtin_amdgcn_mfma_f32_16x16x32_bf16(a[m], b[n], acc[m][n], 0, 0, 0);
  }
  #pragma unroll
  for (int m = 0; m < 6; m++)
    #pragma unroll
    for (int n = 0; n < 4; n++){
      int c = wid * 64 + n * 16 + col;
      #pragma unroll
      for (int r = 0; r < 4; r++){
        int i = m * 16 + quad * 4 + r;
        OH[((size_t)bb * NP + i * 96 + w) * NC + c] = f2bf(acc[m][n][r]);
      }
    }
}

// ---------- 9. outW (MFMA) + total O; T pass stores Ot; S pass fuses loss ----------
__global__ __launch_bounds__(256)
void k_outW(const unsigned short* __restrict__ VT1, const unsigned short* __restrict__ att,
            const unsigned short* __restrict__ OH, unsigned short* __restrict__ Ot,
            const float* __restrict__ predsS, const float* __restrict__ predsT,
            const float* __restrict__ mean, const float* __restrict__ inv,
            const float* __restrict__ gamma, int b0, int spass,
            float* __restrict__ out){
  int h = blockIdx.x, bb = blockIdx.y;    // (96, NB)
  int lane = threadIdx.x & 63, wid = threadIdx.x >> 6;
  int col = lane & 15, quad = lane >> 4;
  floatx4 acc[6][4];
  #pragma unroll
  for (int m = 0; m < 6; m++)
    #pragma unroll
    for (int n = 0; n < 4; n++) acc[m][n] = (floatx4){0.f, 0.f, 0.f, 0.f};
  #pragma unroll
  for (int ks = 0; ks < 3; ks++){
    int k0 = ks * 32 + quad * 8;
    short8 a[6], b[4];
    #pragma unroll
    for (int m = 0; m < 6; m++)
      a[m] = *(const short8*)(att + ((size_t)bb * NP + h * 96 + m * 16 + col) * NL + 96 + k0);
    #pragma unroll
    for (int n = 0; n < 4; n++){
      int c = wid * 64 + n * 16 + col;
      b[n] = *(const short8*)(VT1 + ((size_t)bb * NC + c) * NP + h * 96 + k0);
    }
    #pragma unroll
    for (int m = 0; m < 6; m++)
      #pragma unroll
      for (int n = 0; n < 4; n++)
        acc[m][n] = __builtin_amdgcn_mfma_f32_16x16x32_bf16(a[m], b[n], acc[m][n], 0, 0, 0);
  }
  if (!spass){
    #pragma unroll
    for (int m = 0; m < 6; m++)
      #pragma unroll
      for (int n = 0; n < 4; n++){
        int c = wid * 64 + n * 16 + col;
        #pragma unroll
        for (int r = 0; r < 4; r++){
          int i = m * 16 + quad * 4 + r;
          size_t base = ((size_t)bb * NP + h * 96 + i) * NC + c;
          Ot[base] = f2bf(acc[m][n][r] + bf2f(OH[base]));
        }
      }
  } else {
    int bg = b0 + bb;
    float g = gamma[0];
    float ss = 0.f;
    #pragma unroll
    for (int n = 0; n < 4; n++){
      int c = wid * 64 + n * 16 + col;
      float mS = mean[c],      iS = inv[c];
      float mT = mean[NC + c], iT = inv[NC + c];
      const float* tp = predsT + ((size_t)bg * NC + c) * NP + h * 96;
      const float* sp = predsS + ((size_t)bg * NC + c) * NP + h * 96;
      #pragma unroll
      for (int m = 0; m < 6; m++){
        int i0 = m * 16 + quad * 4;
        F4 tv, sv;
        tv.v = *(const float4*)(tp + i0);
        sv.v = *(const float4*)(sp + i0);
        #pragma unroll
        for (int r = 0; r < 4; r++){
          size_t base = ((size_t)bb * NP + h * 96 + i0 + r) * NC + c;
          float os = acc[m][n][r] + bf2f(OH[base]);
          float ot = bf2f(Ot[base]);
          float dn = (tv.a[r] - mT) * iT - (sv.a[r] - mS) * iS;
          float d = g * (ot - os) + dn;
          ss += d * d;
        }
      }
    }
    ss = blockReduceSum(ss);
    if (threadIdx.x == 0) atomicAdd(out, ss * (1e-5f / 8.0f));
  }
}

// ---------- host ----------
extern "C" void kernel_launch(void* const* d_in, const int* in_sizes, int n_in,
                              void* d_out, int out_size, void* d_ws, size_t ws_size,
                              hipStream_t stream){
  (void)in_sizes; (void)n_in; (void)out_size;
  const float* S    = (const float*)d_in[0];
  const float* T    = (const float*)d_in[1];
  const float* wcls = (const float*)d_in[2];
  const float* wq   = (const float*)d_in[3];
  const float* bq   = (const float*)d_in[4];
  const float* wk   = (const float*)d_in[5];
  const float* bk   = (const float*)d_in[6];
  const float* wv   = (const float*)d_in[7];
  const float* bv   = (const float*)d_in[8];
  const float* gamma= (const float*)d_in[9];
  float* out = (float*)d_out;

  char* base = (char*)d_ws;
  size_t off = 0;
  auto alloc = [&](size_t b){ size_t o = off; off += (b + 255) & ~(size_t)255; return o; };
  size_t o_ssum = alloc(2 * NC * 4);
  size_t o_ssq  = alloc(2 * NC * 4);
  size_t o_mean = alloc(2 * NC * 4);
  size_t o_inv  = alloc(2 * NC * 4);
  size_t o_ca   = alloc((size_t)2 * NBAT * NKC * NC * 4);
  size_t o_smca = alloc((size_t)2 * NBAT * NKC * NP * 4);
  size_t fixed = off;
  size_t per_b = (size_t)NP * NC * 2 * 5       // XN + VT1 + VT2 + OH + Ot (bf16)
               + (size_t)NP * NCQ * 2 * 2      // q + k (bf16)
               + (size_t)NP * NL * 2;          // att (bf16)
  int NB = 8;
  while (NB > 1 && fixed + (size_t)NB * per_b + 8192 > ws_size) NB >>= 1;

  size_t o_xn  = alloc((size_t)NB * NP * NC * 2);
  size_t o_v1  = alloc((size_t)NB * NP * NC * 2);
  size_t o_v2  = alloc((size_t)NB * NP * NC * 2);
  size_t o_q   = alloc((size_t)NB * NP * NCQ * 2);
  size_t o_k   = alloc((size_t)NB * NP * NCQ * 2);
  size_t o_att = alloc((size_t)NB * NP * NL * 2);
  size_t o_oh  = alloc((size_t)NB * NP * NC * 2);
  size_t o_ot  = alloc((size_t)NB * NP * NC * 2);

  float* ssum = (float*)(base + o_ssum);
  float* ssq  = (float*)(base + o_ssq);
  float* mean = (float*)(base + o_mean);
  float* inv  = (float*)(base + o_inv);
  float* ca   = (float*)(base + o_ca);
  float* smca = (float*)(base + o_smca);
  unsigned short* XN  = (unsigned short*)(base + o_xn);
  unsigned short* VT1 = (unsigned short*)(base + o_v1);
  unsigned short* VT2 = (unsigned short*)(base + o_v2);
  unsigned short* qbp = (unsigned short*)(base + o_q);
  unsigned short* kbp = (unsigned short*)(base + o_k);
  unsigned short* att = (unsigned short*)(base + o_att);
  unsigned short* OH  = (unsigned short*)(base + o_oh);
  unsigned short* Ot  = (unsigned short*)(base + o_ot);

  hipMemsetAsync(d_out, 0, 4, stream);
  hipMemsetAsync(base + o_ssum, 0, 4096, stream);
  hipMemsetAsync(base + o_ca, 0, (size_t)2 * NBAT * NKC * NC * 4, stream);

  k_stats<<<dim3(2 * NC * NBAT), 256, 0, stream>>>(S, T, ssum, ssq);
  k_finalize<<<1, 512, 0, stream>>>(ssum, ssq, mean, inv);

  // causal attention (both tensors, full batch)
  k_caM<<<dim3(36, NBAT, 2), 256, 0, stream>>>(S, T, wcls, mean, inv, smca);
  k_caSoftmax<<<dim3(2 * NBAT * NKC), 256, 0, stream>>>(smca);
  k_caOut<<<dim3(48, NBAT, 2), 256, 0, stream>>>(S, T, smca, mean, inv, ca);
  k_caLoss<<<dim3(48), 256, 0, stream>>>(ca, out);

  // ccnet: per batch-chunk, tensor T then S (loss fused into S outW)
  for (int b0 = 0; b0 < NBAT; b0 += NB){
    for (int pass = 0; pass < 2; pass++){
      int t = (pass == 0) ? 1 : 0;
      const float* x = t ? T : S;
      k_xn<<<dim3(144, 4, NB), 256, 0, stream>>>(x, b0, mean, inv, t, XN);
      k_v<<<dim3(144, NB), 256, 0, stream>>>(XN, wv, bv, wq, bq, wk, bk, VT1, qbp, kbp);
      k_vt<<<dim3(NC, NB), 256, 0, stream>>>(VT1, VT2);
      k_eH<<<dim3(96, NB), 256, 0, stream>>>(qbp, kbp, att);
      k_eW<<<dim3(96, NB), 256, 0, stream>>>(qbp, kbp, att);
      k_attSoftmax<<<dim3(NB * 2304), 256, 0, stream>>>(att);
      k_outH<<<dim3(96, NB), 256, 0, stream>>>(VT2, att, OH);
      k_outW<<<dim3(96, NB), 256, 0, stream>>>(VT1, att, OH, Ot, S, T, mean, inv,
                                               gamma, b0, pass, out);
    }
  }
}

// Round 4
// 649.401 us; speedup vs baseline: 2.3706x; 1.1551x over previous
//
#include <hip/hip_runtime.h>
#include <math.h>

#define NBAT 8
#define NC   256
#define NH   96
#define NW   96
#define NP   9216
#define NCQ  32
#define NKC  6
#define NL   192
#define NV   320          // 256 v-channels + 32 q + 32 k
#define NTOT 73728        // NBAT*NP

typedef __attribute__((ext_vector_type(4))) float  floatx4;
typedef __attribute__((ext_vector_type(8))) short  short8;

// ---------- bf16 helpers (storage only; math fp32) ----------
__device__ __forceinline__ float bf2f(unsigned short h){
  return __uint_as_float(((unsigned)h) << 16);
}
__device__ __forceinline__ float bflo(unsigned u){ return __uint_as_float(u << 16); }
__device__ __forceinline__ float bfhi(unsigned u){ return __uint_as_float(u & 0xFFFF0000u); }
__device__ __forceinline__ unsigned short f2bf(float f){
  unsigned u = __float_as_uint(f);
  u += 0x7FFFu + ((u >> 16) & 1u);
  return (unsigned short)(u >> 16);
}

union F4 { float4 v; float a[4]; };

// ---------- reductions ----------
__device__ __forceinline__ float warpReduceSum(float v){
  #pragma unroll
  for (int m = 32; m; m >>= 1) v += __shfl_xor(v, m);
  return v;
}
__device__ __forceinline__ float warpReduceMax(float v){
  #pragma unroll
  for (int m = 32; m; m >>= 1) v = fmaxf(v, __shfl_xor(v, m));
  return v;
}
__device__ float blockReduceSum(float v){
  __shared__ float lds[8];
  v = warpReduceSum(v);
  int wid = threadIdx.x >> 6, lane = threadIdx.x & 63;
  int nw = blockDim.x >> 6;
  if (lane == 0) lds[wid] = v;
  __syncthreads();
  if (wid == 0){
    v = (lane < nw) ? lds[lane] : 0.f;
    #pragma unroll
    for (int m = 4; m; m >>= 1) v += __shfl_xor(v, m);
  }
  __syncthreads();
  return v;  // valid on thread 0
}
__device__ float blockReduceMax(float v){
  __shared__ float lds[8];
  v = warpReduceMax(v);
  int wid = threadIdx.x >> 6, lane = threadIdx.x & 63;
  int nw = blockDim.x >> 6;
  if (lane == 0) lds[wid] = v;
  __syncthreads();
  if (wid == 0){
    v = (lane < nw) ? lds[lane] : -INFINITY;
    #pragma unroll
    for (int m = 4; m; m >>= 1) v = fmaxf(v, __shfl_xor(v, m));
  }
  __syncthreads();
  return v;
}

// ---------- 1. per-channel stats (float4 vectorized) ----------
__global__ __launch_bounds__(256)
void k_stats(const float* __restrict__ S, const float* __restrict__ T,
             float* __restrict__ s_sum, float* __restrict__ s_sq){
  int blk = blockIdx.x;                 // 2*C*B = 4096
  int t = blk / (NC * NBAT);
  int rem = blk % (NC * NBAT);
  int c = rem / NBAT;
  int n = rem % NBAT;
  const float4* x4 = (const float4*)((t ? T : S) + ((size_t)n * NC + c) * NP);
  float s = 0.f, q = 0.f;
  for (int p = threadIdx.x; p < NP / 4; p += 256){
    F4 f; f.v = x4[p];
    #pragma unroll
    for (int j = 0; j < 4; j++){ s += f.a[j]; q += f.a[j] * f.a[j]; }
  }
  s = blockReduceSum(s);
  q = blockReduceSum(q);
  if (threadIdx.x == 0){
    atomicAdd(&s_sum[t * NC + c], s);
    atomicAdd(&s_sq[t * NC + c], q);
  }
}

__global__ __launch_bounds__(512)
void k_finalize(const float* __restrict__ s_sum, const float* __restrict__ s_sq,
                float* __restrict__ mean, float* __restrict__ inv){
  int i = threadIdx.x;
  if (i < 2 * NC){
    float s = s_sum[i], q = s_sq[i];
    float m = s / (float)NTOT;
    float var = (q - s * m) / (float)(NTOT - 1);
    var = fmaxf(var, 0.f);
    mean[i] = m;
    inv[i] = 1.f / (sqrtf(var) + 1e-6f);
  }
}

// ---------- 2. causal attention ----------
__global__ __launch_bounds__(256)
void k_caM(const float* __restrict__ S, const float* __restrict__ T,
           const float* __restrict__ wcls,
           const float* __restrict__ mean, const float* __restrict__ inv,
           float* __restrict__ smca){
  int pt = blockIdx.x, n = blockIdx.y, t = blockIdx.z;   // (36, 8, 2)
  __shared__ float wsc[NKC * NC];
  __shared__ float shift[NKC];
  for (int idx = threadIdx.x; idx < NKC * NC; idx += 256){
    int c = idx & 255;
    wsc[idx] = wcls[idx] * inv[t * NC + c];
  }
  __syncthreads();
  if (threadIdx.x < NKC){
    float sh = 0.f;
    for (int c = 0; c < NC; c++) sh += wsc[threadIdx.x * NC + c] * mean[t * NC + c];
    shift[threadIdx.x] = sh;
  }
  __syncthreads();
  int p = pt * 256 + threadIdx.x;
  const float* x = (t ? T : S) + (size_t)n * NC * NP + p;
  float acc[NKC];
  #pragma unroll
  for (int k = 0; k < NKC; k++) acc[k] = 0.f;
  for (int c = 0; c < NC; c++){
    float xv = x[(size_t)c * NP];
    #pragma unroll
    for (int k = 0; k < NKC; k++) acc[k] += wsc[k * NC + c] * xv;
  }
  size_t base = ((size_t)(t * NBAT + n) * NKC) * NP + p;
  #pragma unroll
  for (int k = 0; k < NKC; k++) smca[base + (size_t)k * NP] = acc[k] - shift[k];
}

__global__ __launch_bounds__(256)
void k_caSoftmax(float* __restrict__ smca){
  int r = blockIdx.x;                      // 96 rows
  float* row = smca + (size_t)r * NP;
  float m = -INFINITY;
  for (int p = threadIdx.x; p < NP; p += 256) m = fmaxf(m, row[p]);
  m = blockReduceMax(m);
  __shared__ float bm, bs;
  if (threadIdx.x == 0) bm = m;
  __syncthreads();
  m = bm;
  float s = 0.f;
  for (int p = threadIdx.x; p < NP; p += 256) s += expf(row[p] - m);
  s = blockReduceSum(s);
  if (threadIdx.x == 0) bs = 1.f / s;
  __syncthreads();
  float rs = bs;
  for (int p = threadIdx.x; p < NP; p += 256) row[p] = expf(row[p] - m) * rs;
}

// split-K caOut: grid.x = ct(8) + 8*ks(6)
__global__ __launch_bounds__(256)
void k_caOut(const float* __restrict__ S, const float* __restrict__ T,
             const float* __restrict__ smca,
             const float* __restrict__ mean, const float* __restrict__ inv,
             float* __restrict__ ca){
  int ct = blockIdx.x & 7, ks = blockIdx.x >> 3;
  int n = blockIdx.y, t = blockIdx.z;   // (48, 8, 2)
  int c0 = ct * 32;
  __shared__ float xt[32 * 264];
  __shared__ float smt[NKC * 256];
  int cl = threadIdx.x >> 3, pl = threadIdx.x & 7;
  float acc[NKC];
  #pragma unroll
  for (int k = 0; k < NKC; k++) acc[k] = 0.f;
  const float* xbase = (t ? T : S) + (size_t)n * NC * NP;
  const float* smbase = smca + (size_t)(t * NBAT + n) * NKC * NP;
  for (int pt = ks * 6; pt < ks * 6 + 6; pt++){
    int p0 = pt * 256;
    for (int idx = threadIdx.x; idx < 32 * 256; idx += 256){
      int r = idx >> 8, p = idx & 255;
      float v = xbase[(size_t)(c0 + r) * NP + p0 + p];
      xt[r * 264 + p] = (v - mean[t * NC + c0 + r]) * inv[t * NC + c0 + r];
    }
    for (int idx = threadIdx.x; idx < NKC * 256; idx += 256){
      int k = idx >> 8, p = idx & 255;
      smt[idx] = smbase[(size_t)k * NP + p0 + p];
    }
    __syncthreads();
    for (int j = 0; j < 32; j++){
      float xv = xt[cl * 264 + pl + 8 * j];
      #pragma unroll
      for (int k = 0; k < NKC; k++) acc[k] += smt[k * 256 + pl + 8 * j] * xv;
    }
    __syncthreads();
  }
  #pragma unroll
  for (int k = 0; k < NKC; k++){
    float v = acc[k];
    v += __shfl_xor(v, 1); v += __shfl_xor(v, 2); v += __shfl_xor(v, 4);
    if (pl == 0) atomicAdd(&ca[((size_t)(t * NBAT + n) * NKC + k) * NC + c0 + cl], v);
  }
}

__global__ __launch_bounds__(256)
void k_caLoss(const float* __restrict__ ca, float* __restrict__ out){
  int i = blockIdx.x * 256 + threadIdx.x;   // 12288 total
  float d = 0.f;
  if (i < NBAT * NKC * NC) d = ca[(size_t)NBAT * NKC * NC + i] - ca[i];
  float ss = blockReduceSum(d * d);
  if (threadIdx.x == 0) atomicAdd(out, ss * (0.0005f / 8.0f));
}

// ---------- 3. stage normalized x as bf16 XN[b][p][c] (transpose) ----------
__global__ __launch_bounds__(256)
void k_xn(const float* __restrict__ x0, int b0,
          const float* __restrict__ mean, const float* __restrict__ inv, int t,
          unsigned short* __restrict__ XN){
  int pt = blockIdx.x, ct = blockIdx.y, bb = blockIdx.z;  // (144, 4, NB)
  int bg = b0 + bb;
  int p0 = pt * 64, c0 = ct * 64;
  __shared__ float tile[64 * 65];
  const float* x = x0 + ((size_t)bg * NC + c0) * NP + p0;
  #pragma unroll
  for (int i = 0; i < 4; i++){
    int idx = threadIdx.x + i * 256;       // 64 c-rows x 16 float4 groups
    int r = idx >> 4, g = (idx & 15) * 4;
    F4 f; f.v = *(const float4*)(x + (size_t)r * NP + g);
    float m = mean[t * NC + c0 + r], iv = inv[t * NC + c0 + r];
    #pragma unroll
    for (int j = 0; j < 4; j++) tile[(g + j) * 65 + r] = (f.a[j] - m) * iv;
  }
  __syncthreads();
  #pragma unroll
  for (int i = 0; i < 4; i++){
    int idx = threadIdx.x + i * 256;       // 64 p-rows x 16 groups of 4c
    int p = idx >> 4, g = (idx & 15) * 4;
    unsigned lo = (unsigned)f2bf(tile[p * 65 + g + 0]) | ((unsigned)f2bf(tile[p * 65 + g + 1]) << 16);
    unsigned hi = (unsigned)f2bf(tile[p * 65 + g + 2]) | ((unsigned)f2bf(tile[p * 65 + g + 3]) << 16);
    uint2 u; u.x = lo; u.y = hi;
    *(uint2*)(XN + ((size_t)bb * NP + p0 + p) * NC + c0 + g) = u;
  }
}

// ---------- 3b. pre-convert W (v|q|k) to bf16 Wb[320][256], once per launch ----------
__global__ __launch_bounds__(256)
void k_wconv(const float* __restrict__ wv, const float* __restrict__ wq,
             const float* __restrict__ wk, unsigned short* __restrict__ Wb){
  int n = blockIdx.x;         // 320
  const float* src = (n < 256) ? (wv + (size_t)n * NC)
                   : (n < 288) ? (wq + (size_t)(n - 256) * NC)
                               : (wk + (size_t)(n - 288) * NC);
  Wb[(size_t)n * NC + threadIdx.x] = f2bf(src[threadIdx.x]);
}

// ---------- 4. MFMA GEMM: XN[p x 256] @ Wb^T -> VT1[b][c][p] + q,k [p][cq] ----------
// software-pipelined: slice ks+1 global->reg load in flight during MFMA of slice ks
__global__ __launch_bounds__(256)
void k_v(const unsigned short* __restrict__ XN, const unsigned short* __restrict__ Wb,
         const float* __restrict__ bv, const float* __restrict__ bq,
         const float* __restrict__ bk,
         unsigned short* __restrict__ VT1,
         unsigned short* __restrict__ qb, unsigned short* __restrict__ kb){
  int pt = blockIdx.x, bb = blockIdx.y;   // (144, NB)
  int p0 = pt * 64;
  __shared__ unsigned short Wl[NV * 40];  // stride 40 shorts (80B, 16B-aligned rows)
  int lane = threadIdx.x & 63;
  int wid = threadIdx.x >> 6;
  int col = lane & 15, quad = lane >> 4;
  const unsigned short* xnb = XN + (size_t)bb * NP * NC + (size_t)(p0 + wid * 16 + col) * NC;
  floatx4 acc[20];
  #pragma unroll
  for (int nt = 0; nt < 20; nt++) acc[nt] = (floatx4){0.f, 0.f, 0.f, 0.f};

  // staging chunk map: ci = i*256+tid; n = ci>>2, k8 = ci&3 (4 x short8 per 32-k row)
  int ci_n[5], ci_k8[5];
  #pragma unroll
  for (int i = 0; i < 5; i++){ int ci = i * 256 + threadIdx.x; ci_n[i] = ci >> 2; ci_k8[i] = (ci & 3) * 8; }

  short8 w[5];
  #pragma unroll
  for (int i = 0; i < 5; i++)
    w[i] = *(const short8*)(Wb + (size_t)ci_n[i] * NC + ci_k8[i]);

  for (int ks = 0; ks < 8; ks++){
    if (ks) __syncthreads();              // previous slice's reads done
    #pragma unroll
    for (int i = 0; i < 5; i++)
      *(short8*)(Wl + ci_n[i] * 40 + ci_k8[i]) = w[i];
    __syncthreads();
    if (ks < 7){
      int k0n = (ks + 1) * 32;
      #pragma unroll
      for (int i = 0; i < 5; i++)
        w[i] = *(const short8*)(Wb + (size_t)ci_n[i] * NC + k0n + ci_k8[i]);
    }
    short8 a = *(const short8*)(xnb + ks * 32 + quad * 8);
    #pragma unroll
    for (int nt = 0; nt < 20; nt++){
      short8 b = *(const short8*)(Wl + (nt * 16 + col) * 40 + quad * 8);
      acc[nt] = __builtin_amdgcn_mfma_f32_16x16x32_bf16(a, b, acc[nt], 0, 0, 0);
    }
  }

  int prow0 = p0 + wid * 16 + quad * 4;
  #pragma unroll
  for (int nt = 0; nt < 16; nt++){
    int c = nt * 16 + col;
    float bias = bv[c];
    uint2 u;
    u.x = (unsigned)f2bf(acc[nt][0] + bias) | ((unsigned)f2bf(acc[nt][1] + bias) << 16);
    u.y = (unsigned)f2bf(acc[nt][2] + bias) | ((unsigned)f2bf(acc[nt][3] + bias) << 16);
    *(uint2*)(VT1 + ((size_t)bb * NC + c) * NP + prow0) = u;
  }
  #pragma unroll
  for (int nt = 16; nt < 18; nt++){
    int c = (nt - 16) * 16 + col;
    float bias = bq[c];
    #pragma unroll
    for (int i = 0; i < 4; i++)
      qb[((size_t)bb * NP + prow0 + i) * NCQ + c] = f2bf(acc[nt][i] + bias);
  }
  #pragma unroll
  for (int nt = 18; nt < 20; nt++){
    int c = (nt - 18) * 16 + col;
    float bias = bk[c];
    #pragma unroll
    for (int i = 0; i < 4; i++)
      kb[((size_t)bb * NP + prow0 + i) * NCQ + c] = f2bf(acc[nt][i] + bias);
  }
}

// ---------- 4b. spatial transpose: VT2[b][c][w*96+h] = VT1[b][c][h*96+w] ----------
__global__ __launch_bounds__(256)
void k_vt(const unsigned short* __restrict__ VT1, unsigned short* __restrict__ VT2){
  int c = blockIdx.x, bb = blockIdx.y;    // (256, NB)
  __shared__ unsigned short tile[96 * 104];  // [w][h], stride 104 (16B-aligned rows)
  size_t base = ((size_t)bb * NC + c) * NP;
  for (int idx = threadIdx.x; idx < 1152; idx += 256){
    int h = idx / 12, g = idx % 12;
    short8 v = *(const short8*)(VT1 + base + h * 96 + g * 8);
    #pragma unroll
    for (int kk = 0; kk < 8; kk++) tile[(g * 8 + kk) * 104 + h] = ((unsigned short*)&v)[kk];
  }
  __syncthreads();
  for (int idx = threadIdx.x; idx < 1152; idx += 256){
    int w = idx / 12, g = idx % 12;
    short8 v = *(const short8*)(tile + w * 104 + g * 8);
    *(short8*)(VT2 + base + w * 96 + g * 8) = v;
  }
}

// ---------- 5. eH scores (MFMA, diag masked): att[b][i*96+w][j], j<96 ----------
__global__ __launch_bounds__(256)
void k_eH(const unsigned short* __restrict__ qb, const unsigned short* __restrict__ kb,
          unsigned short* __restrict__ att){
  int w = blockIdx.x, bb = blockIdx.y;      // (96, NB)
  int lane = threadIdx.x & 63, wid = threadIdx.x >> 6;
  int col = lane & 15, quad = lane >> 4;
  int mi0 = (wid & 1) * 3, ni0 = (wid >> 1) * 3;
  short8 a[3], b[3];
  #pragma unroll
  for (int m = 0; m < 3; m++)
    a[m] = *(const short8*)(qb + ((size_t)bb * NP + ((mi0 + m) * 16 + col) * 96 + w) * NCQ + quad * 8);
  #pragma unroll
  for (int n = 0; n < 3; n++)
    b[n] = *(const short8*)(kb + ((size_t)bb * NP + ((ni0 + n) * 16 + col) * 96 + w) * NCQ + quad * 8);
  floatx4 acc[3][3];
  #pragma unroll
  for (int m = 0; m < 3; m++)
    #pragma unroll
    for (int n = 0; n < 3; n++){
      acc[m][n] = (floatx4){0.f, 0.f, 0.f, 0.f};
      acc[m][n] = __builtin_amdgcn_mfma_f32_16x16x32_bf16(a[m], b[n], acc[m][n], 0, 0, 0);
    }
  #pragma unroll
  for (int m = 0; m < 3; m++)
    #pragma unroll
    for (int n = 0; n < 3; n++){
      int j = (ni0 + n) * 16 + col;
      #pragma unroll
      for (int r = 0; r < 4; r++){
        int i = (mi0 + m) * 16 + quad * 4 + r;
        float v = (j == i) ? -INFINITY : acc[m][n][r];
        att[((size_t)bb * NP + i * 96 + w) * NL + j] = f2bf(v);
      }
    }
}

// ---------- 6. eW scores (MFMA): att[b][h*96+i][96+j] ----------
__global__ __launch_bounds__(256)
void k_eW(const unsigned short* __restrict__ qb, const unsigned short* __restrict__ kb,
          unsigned short* __restrict__ att){
  int h = blockIdx.x, bb = blockIdx.y;      // (96, NB)
  int lane = threadIdx.x & 63, wid = threadIdx.x >> 6;
  int col = lane & 15, quad = lane >> 4;
  int mi0 = (wid & 1) * 3, ni0 = (wid >> 1) * 3;
  short8 a[3], b[3];
  #pragma unroll
  for (int m = 0; m < 3; m++)
    a[m] = *(const short8*)(qb + ((size_t)bb * NP + h * 96 + (mi0 + m) * 16 + col) * NCQ + quad * 8);
  #pragma unroll
  for (int n = 0; n < 3; n++)
    b[n] = *(const short8*)(kb + ((size_t)bb * NP + h * 96 + (ni0 + n) * 16 + col) * NCQ + quad * 8);
  floatx4 acc[3][3];
  #pragma unroll
  for (int m = 0; m < 3; m++)
    #pragma unroll
    for (int n = 0; n < 3; n++){
      acc[m][n] = (floatx4){0.f, 0.f, 0.f, 0.f};
      acc[m][n] = __builtin_amdgcn_mfma_f32_16x16x32_bf16(a[m], b[n], acc[m][n], 0, 0, 0);
    }
  #pragma unroll
  for (int m = 0; m < 3; m++)
    #pragma unroll
    for (int n = 0; n < 3; n++){
      int j = (ni0 + n) * 16 + col;
      #pragma unroll
      for (int r = 0; r < 4; r++){
        int i = (mi0 + m) * 16 + quad * 4 + r;
        att[((size_t)bb * NP + h * 96 + i) * NL + 96 + j] = f2bf(acc[m][n][r]);
      }
    }
}

// ---------- 7. softmax over 192 per query ----------
__global__ __launch_bounds__(256)
void k_attSoftmax(unsigned short* __restrict__ att){
  int q = blockIdx.x * 4 + (threadIdx.x >> 6);
  int lane = threadIdx.x & 63;
  unsigned short* row = att + (size_t)q * NL;
  float e0 = bf2f(row[lane]);
  float e1 = bf2f(row[64 + lane]);
  float e2 = bf2f(row[128 + lane]);
  float m = fmaxf(e0, fmaxf(e1, e2));
  m = warpReduceMax(m);
  float x0 = expf(e0 - m), x1 = expf(e1 - m), x2 = expf(e2 - m);
  float s = warpReduceSum(x0 + x1 + x2);
  float rs = 1.f / s;
  row[lane]       = f2bf(x0 * rs);
  row[64 + lane]  = f2bf(x1 * rs);
  row[128 + lane] = f2bf(x2 * rs);
}

// ---------- 8. outH (MFMA): OH[i*96+w][c] = sum_j attH[(i,w),j] * VT2[c][w*96+j] ----------
__global__ __launch_bounds__(256)
void k_outH(const unsigned short* __restrict__ VT2, const unsigned short* __restrict__ att,
            unsigned short* __restrict__ OH){
  int w = blockIdx.x, bb = blockIdx.y;    // (96, NB)
  int lane = threadIdx.x & 63, wid = threadIdx.x >> 6;
  int col = lane & 15, quad = lane >> 4;
  floatx4 acc[6][4];
  #pragma unroll
  for (int m = 0; m < 6; m++)
    #pragma unroll
    for (int n = 0; n < 4; n++) acc[m][n] = (floatx4){0.f, 0.f, 0.f, 0.f};
  #pragma unroll
  for (int ks = 0; ks < 3; ks++){
    int k0 = ks * 32 + quad * 8;
    short8 a[6], b[4];
    #pragma unroll
    for (int m = 0; m < 6; m++)
      a[m] = *(const short8*)(att + ((size_t)bb * NP + (m * 16 + col) * 96 + w) * NL + k0);
    #pragma unroll
    for (int n = 0; n < 4; n++){
      int c = wid * 64 + n * 16 + col;
      b[n] = *(const short8*)(VT2 + ((size_t)bb * NC + c) * NP + w * 96 + k0);
    }
    #pragma unroll
    for (int m = 0; m < 6; m++)
      #pragma unroll
      for (int n = 0; n < 4; n++)
        acc[m][n] = __builtin_amdgcn_mfma_f32_16x16x32_bf16(a[m], b[n], acc[m][n], 0, 0, 0);
  }
  #pragma unroll
  for (int m = 0; m < 6; m++)
    #pragma unroll
    for (int n = 0; n < 4; n++){
      int c = wid * 64 + n * 16 + col;
      #pragma unroll
      for (int r = 0; r < 4; r++){
        int i = m * 16 + quad * 4 + r;
        OH[((size_t)bb * NP + i * 96 + w) * NC + c] = f2bf(acc[m][n][r]);
      }
    }
}

// ---------- 9. outW (MFMA) + total O; T pass stores Ot; S pass fuses loss ----------
__global__ __launch_bounds__(256)
void k_outW(const unsigned short* __restrict__ VT1, const unsigned short* __restrict__ att,
            const unsigned short* __restrict__ OH, unsigned short* __restrict__ Ot,
            const float* __restrict__ predsS, const float* __restrict__ predsT,
            const float* __restrict__ mean, const float* __restrict__ inv,
            const float* __restrict__ gamma, int b0, int spass,
            float* __restrict__ out){
  int h = blockIdx.x, bb = blockIdx.y;    // (96, NB)
  int lane = threadIdx.x & 63, wid = threadIdx.x >> 6;
  int col = lane & 15, quad = lane >> 4;
  floatx4 acc[6][4];
  #pragma unroll
  for (int m = 0; m < 6; m++)
    #pragma unroll
    for (int n = 0; n < 4; n++) acc[m][n] = (floatx4){0.f, 0.f, 0.f, 0.f};
  #pragma unroll
  for (int ks = 0; ks < 3; ks++){
    int k0 = ks * 32 + quad * 8;
    short8 a[6], b[4];
    #pragma unroll
    for (int m = 0; m < 6; m++)
      a[m] = *(const short8*)(att + ((size_t)bb * NP + h * 96 + m * 16 + col) * NL + 96 + k0);
    #pragma unroll
    for (int n = 0; n < 4; n++){
      int c = wid * 64 + n * 16 + col;
      b[n] = *(const short8*)(VT1 + ((size_t)bb * NC + c) * NP + h * 96 + k0);
    }
    #pragma unroll
    for (int m = 0; m < 6; m++)
      #pragma unroll
      for (int n = 0; n < 4; n++)
        acc[m][n] = __builtin_amdgcn_mfma_f32_16x16x32_bf16(a[m], b[n], acc[m][n], 0, 0, 0);
  }
  if (!spass){
    #pragma unroll
    for (int m = 0; m < 6; m++)
      #pragma unroll
      for (int n = 0; n < 4; n++){
        int c = wid * 64 + n * 16 + col;
        #pragma unroll
        for (int r = 0; r < 4; r++){
          int i = m * 16 + quad * 4 + r;
          size_t base = ((size_t)bb * NP + h * 96 + i) * NC + c;
          Ot[base] = f2bf(acc[m][n][r] + bf2f(OH[base]));
        }
      }
  } else {
    int bg = b0 + bb;
    float g = gamma[0];
    float ss = 0.f;
    #pragma unroll
    for (int n = 0; n < 4; n++){
      int c = wid * 64 + n * 16 + col;
      float mS = mean[c],      iS = inv[c];
      float mT = mean[NC + c], iT = inv[NC + c];
      const float* tp = predsT + ((size_t)bg * NC + c) * NP + h * 96;
      const float* sp = predsS + ((size_t)bg * NC + c) * NP + h * 96;
      #pragma unroll
      for (int m = 0; m < 6; m++){
        int i0 = m * 16 + quad * 4;
        F4 tv, sv;
        tv.v = *(const float4*)(tp + i0);
        sv.v = *(const float4*)(sp + i0);
        #pragma unroll
        for (int r = 0; r < 4; r++){
          size_t base = ((size_t)bb * NP + h * 96 + i0 + r) * NC + c;
          float os = acc[m][n][r] + bf2f(OH[base]);
          float ot = bf2f(Ot[base]);
          float dn = (tv.a[r] - mT) * iT - (sv.a[r] - mS) * iS;
          float d = g * (ot - os) + dn;
          ss += d * d;
        }
      }
    }
    ss = blockReduceSum(ss);
    if (threadIdx.x == 0) atomicAdd(out, ss * (1e-5f / 8.0f));
  }
}

// ---------- host ----------
extern "C" void kernel_launch(void* const* d_in, const int* in_sizes, int n_in,
                              void* d_out, int out_size, void* d_ws, size_t ws_size,
                              hipStream_t stream){
  (void)in_sizes; (void)n_in; (void)out_size;
  const float* S    = (const float*)d_in[0];
  const float* T    = (const float*)d_in[1];
  const float* wcls = (const float*)d_in[2];
  const float* wq   = (const float*)d_in[3];
  const float* bq   = (const float*)d_in[4];
  const float* wk   = (const float*)d_in[5];
  const float* bk   = (const float*)d_in[6];
  const float* wv   = (const float*)d_in[7];
  const float* bv   = (const float*)d_in[8];
  const float* gamma= (const float*)d_in[9];
  float* out = (float*)d_out;

  char* base = (char*)d_ws;
  size_t off = 0;
  auto alloc = [&](size_t b){ size_t o = off; off += (b + 255) & ~(size_t)255; return o; };
  size_t o_ssum = alloc(2 * NC * 4);
  size_t o_ssq  = alloc(2 * NC * 4);
  size_t o_mean = alloc(2 * NC * 4);
  size_t o_inv  = alloc(2 * NC * 4);
  size_t o_wb   = alloc((size_t)NV * NC * 2);
  size_t o_ca   = alloc((size_t)2 * NBAT * NKC * NC * 4);
  size_t o_smca = alloc((size_t)2 * NBAT * NKC * NP * 4);
  size_t fixed = off;
  size_t per_b = (size_t)NP * NC * 2 * 5       // XN + VT1 + VT2 + OH + Ot (bf16)
               + (size_t)NP * NCQ * 2 * 2      // q + k (bf16)
               + (size_t)NP * NL * 2;          // att (bf16)
  int NB = 8;
  while (NB > 1 && fixed + (size_t)NB * per_b + 8192 > ws_size) NB >>= 1;

  size_t o_xn  = alloc((size_t)NB * NP * NC * 2);
  size_t o_v1  = alloc((size_t)NB * NP * NC * 2);
  size_t o_v2  = alloc((size_t)NB * NP * NC * 2);
  size_t o_q   = alloc((size_t)NB * NP * NCQ * 2);
  size_t o_k   = alloc((size_t)NB * NP * NCQ * 2);
  size_t o_att = alloc((size_t)NB * NP * NL * 2);
  size_t o_oh  = alloc((size_t)NB * NP * NC * 2);
  size_t o_ot  = alloc((size_t)NB * NP * NC * 2);

  float* ssum = (float*)(base + o_ssum);
  float* ssq  = (float*)(base + o_ssq);
  float* mean = (float*)(base + o_mean);
  float* inv  = (float*)(base + o_inv);
  float* ca   = (float*)(base + o_ca);
  float* smca = (float*)(base + o_smca);
  unsigned short* Wb  = (unsigned short*)(base + o_wb);
  unsigned short* XN  = (unsigned short*)(base + o_xn);
  unsigned short* VT1 = (unsigned short*)(base + o_v1);
  unsigned short* VT2 = (unsigned short*)(base + o_v2);
  unsigned short* qbp = (unsigned short*)(base + o_q);
  unsigned short* kbp = (unsigned short*)(base + o_k);
  unsigned short* att = (unsigned short*)(base + o_att);
  unsigned short* OH  = (unsigned short*)(base + o_oh);
  unsigned short* Ot  = (unsigned short*)(base + o_ot);

  hipMemsetAsync(d_out, 0, 4, stream);
  hipMemsetAsync(base + o_ssum, 0, 4096, stream);
  hipMemsetAsync(base + o_ca, 0, (size_t)2 * NBAT * NKC * NC * 4, stream);

  k_stats<<<dim3(2 * NC * NBAT), 256, 0, stream>>>(S, T, ssum, ssq);
  k_finalize<<<1, 512, 0, stream>>>(ssum, ssq, mean, inv);
  k_wconv<<<dim3(NV), 256, 0, stream>>>(wv, wq, wk, Wb);

  // causal attention (both tensors, full batch)
  k_caM<<<dim3(36, NBAT, 2), 256, 0, stream>>>(S, T, wcls, mean, inv, smca);
  k_caSoftmax<<<dim3(2 * NBAT * NKC), 256, 0, stream>>>(smca);
  k_caOut<<<dim3(48, NBAT, 2), 256, 0, stream>>>(S, T, smca, mean, inv, ca);
  k_caLoss<<<dim3(48), 256, 0, stream>>>(ca, out);

  // ccnet: per batch-chunk, tensor T then S (loss fused into S outW)
  for (int b0 = 0; b0 < NBAT; b0 += NB){
    for (int pass = 0; pass < 2; pass++){
      int t = (pass == 0) ? 1 : 0;
      const float* x = t ? T : S;
      k_xn<<<dim3(144, 4, NB), 256, 0, stream>>>(x, b0, mean, inv, t, XN);
      k_v<<<dim3(144, NB), 256, 0, stream>>>(XN, Wb, bv, bq, bk, VT1, qbp, kbp);
      k_vt<<<dim3(NC, NB), 256, 0, stream>>>(VT1, VT2);
      k_eH<<<dim3(96, NB), 256, 0, stream>>>(qbp, kbp, att);
      k_eW<<<dim3(96, NB), 256, 0, stream>>>(qbp, kbp, att);
      k_attSoftmax<<<dim3(NB * 2304), 256, 0, stream>>>(att);
      k_outH<<<dim3(96, NB), 256, 0, stream>>>(VT2, att, OH);
      k_outW<<<dim3(96, NB), 256, 0, stream>>>(VT1, att, OH, Ot, S, T, mean, inv,
                                               gamma, b0, pass, out);
    }
  }
}